// Round 4
// baseline (884.650 us; speedup 1.0000x reference)
//
#include <hip/hip_runtime.h>
#include <cstddef>
#include <cstdint>
#include <cmath>

#define TAU_INV 20.0f
#define NMAT 36
#define BATCH 512
#define MROWS 18432   // 512 * 36
#define MHALF 9216

typedef unsigned short us16;
typedef __attribute__((ext_vector_type(8))) short s16x8;   // 8 bf16 = 4 VGPRs
typedef __attribute__((ext_vector_type(4))) float f32x4;

// ---------------- bf16 helpers (RNE) ----------------
__device__ inline us16 f2bf(float x) {
    uint32_t u = __float_as_uint(x);
    u += 0x7fff + ((u >> 16) & 1);
    return (us16)(u >> 16);
}
__device__ inline float bf2f(us16 h) {
    return __uint_as_float(((uint32_t)h) << 16);
}
// 3-way split: x ~= h + m + l, residual <= 2^-27 |x| (scalar, weights only)
__device__ inline void split3(float v, us16& h, us16& m, us16& l) {
    h = f2bf(v);
    float r1 = v - bf2f(h);
    m = f2bf(r1);
    l = f2bf(r1 - bf2f(m));
}

// packed f32x2 -> bf16x2 convert (T12 recipe; no builtin on gfx950)
__device__ inline uint32_t cvtpk(float lo, float hi) {
    uint32_t d;
    asm("v_cvt_pk_bf16_f32 %0, %1, %2" : "=v"(d) : "v"(lo), "v"(hi));
    return d;
}
// split 4 floats into packed h/m/l bf16 plane words (residuals exact)
__device__ inline void split4pk(const float4& v, uint2& h, uint2& m, uint2& l) {
    uint32_t h0 = cvtpk(v.x, v.y), h1 = cvtpk(v.z, v.w);
    float a0 = v.x - __uint_as_float(h0 << 16);
    float a1 = v.y - __uint_as_float(h0 & 0xffff0000u);
    float a2 = v.z - __uint_as_float(h1 << 16);
    float a3 = v.w - __uint_as_float(h1 & 0xffff0000u);
    uint32_t m0 = cvtpk(a0, a1), m1 = cvtpk(a2, a3);
    a0 -= __uint_as_float(m0 << 16);
    a1 -= __uint_as_float(m0 & 0xffff0000u);
    a2 -= __uint_as_float(m1 << 16);
    a3 -= __uint_as_float(m1 & 0xffff0000u);
    uint32_t l0 = cvtpk(a0, a1), l1 = cvtpk(a2, a3);
    h = make_uint2(h0, h1); m = make_uint2(m0, m1); l = make_uint2(l0, l1);
}

// ---------------- async global->LDS 16B DMA ----------------
__device__ inline void dma16(const void* g, void* l) {
    __builtin_amdgcn_global_load_lds(
        (const __attribute__((address_space(1))) void*)g,
        (__attribute__((address_space(3))) void*)l, 16, 0, 0);
}

__device__ inline f32x4 mfma16(s16x8 a, s16x8 b, f32x4 c) {
    return __builtin_amdgcn_mfma_f32_16x16x32_bf16(a, b, c, 0, 0, 0);
}

// ---------------------------------------------------------------------------
// 3-way-split bf16 MFMA GEMM:  C = act(X @ W^T + bias)  (fp32-equivalent)
//   X: fp32 [M][ldx] (split on the fly, cvt_pk), W: pre-split bf16 planes.
// Pipelined k-loop (T3-minimum): B LDS double-buffered, A LDS single-buffered
// with ping-pong prefetch regs. All global/DMA issue at TOP of iteration so
// the (compiler-forced) vmcnt(0) barrier drains are hidden under compute:
//   iter t: [DMA B(t+1)->Bs[^1]; load prefB=A(t+2)]  (early issue)
//           compute tile t (As, Bs[t&1])              (~1000+ cyc)
//           barrier1  (drains: DMA/loads issued ~1000 cyc ago -> ~free)
//           split prefA(=A(t+1)) -> As; prefA=prefB
//           barrier2  (ds_writes only -> ~free)
// LDS swizzle (verified R3: SQ_LDS_BANK_CONFLICT = 0): us16 idx =
//   row*32 + ((slot8 ^ ((row>>1)&3))*8 + e); A swizzled write+read;
//   B linear DMA dest + pre-swizzled global source col + swizzled read.
// OUT: 0 = relu; 1 = tanh with col<nreal store guard.
// 256 threads = 4 waves, 2x2 wave grid; wave tile (BM/2)x(BN/2).
// ---------------------------------------------------------------------------
template<int BM, int BN, int OUT>
__global__ __launch_bounds__(256, 2)
void gemm_split(const float* __restrict__ X, int ldx,
                const us16* __restrict__ Bh, const us16* __restrict__ Bm,
                const us16* __restrict__ Bl,
                const float* __restrict__ bias,
                float* __restrict__ C, int ldc, int nreal, int K)
{
    constexpr int MT  = BM / 32;      // 16-row m-tiles per wave
    constexpr int NT  = BN / 32;      // 16-col n-tiles per wave
    constexpr int NF4 = BM / 32;      // float4 A-loads per thread per k-tile
    constexpr int LB  = BN / 64;      // B DMA chunks per wave per plane

    // A: 3 planes single-buffered; B: 3 planes x 2 buffers.
    // <64,128>: 12KB + 48KB = 60KB (2 blocks/CU). <64,64>: 36KB.
    alignas(16) __shared__ us16 As[BM * 96];
    alignas(16) __shared__ us16 Bs[2][BN * 96];

    const int tid  = threadIdx.x;
    const int lane = tid & 63;
    const int wid  = tid >> 6;
    const int bm   = blockIdx.x * BM;
    const int bn   = blockIdx.y * BN;
    const int lm   = lane & 15;       // fragment row/col within 16
    const int kb   = lane >> 4;       // k-quad 0..3
    const int wm   = (wid >> 1) * (BM / 2);
    const int wn   = (wid & 1) * (BN / 2);

    // A staging map: thread covers rows arow + i*32, cols acol..acol+3
    const int arow = tid >> 3;        // 0..31
    const int acol = (tid & 7) * 4;   // 0,4,..,28
    const int asw  = ((arow >> 1) & 3) << 3;   // A write swizzle (us16 idx bits 3-4)
    const int fsw  = ((lm >> 1) & 3) << 3;     // fragment read swizzle

    f32x4 acc[MT][NT];
#pragma unroll
    for (int i = 0; i < MT; ++i)
#pragma unroll
        for (int j = 0; j < NT; ++j) acc[i][j] = (f32x4){0.f, 0.f, 0.f, 0.f};

    // B DMA: linear dest (wave-uniform base + lane*16B), pre-swizzled src col
    const int bcol = ((lane & 3) ^ ((lane >> 3) & 3)) * 8;
    const int nk = K / 32;

    // ---- prologue: tile0 -> As/Bs[0]; prefA <- tile1 ----
    float4 prefA[NF4], prefB[NF4];
#pragma unroll
    for (int i = 0; i < NF4; ++i)
        prefA[i] = *(const float4*)(X + (size_t)(bm + i * 32 + arow) * ldx + acol);
#pragma unroll
    for (int i = 0; i < NF4; ++i) {
        const int r = i * 32 + arow;
        uint2 h, m, l;
        split4pk(prefA[i], h, m, l);
        *(uint2*)&As[r * 32 + (acol ^ asw)] = h;
        *(uint2*)&As[BM * 32 + r * 32 + (acol ^ asw)] = m;
        *(uint2*)&As[BM * 64 + r * 32 + (acol ^ asw)] = l;
    }
#pragma unroll
    for (int q = 0; q < LB; ++q) {
        const int rb = wid * (LB * 16) + q * 16;          // wave-uniform
        const int gr = bn + rb + (lane >> 2);
        dma16(Bh + (size_t)gr * K + bcol, &Bs[0][rb * 32]);
        dma16(Bm + (size_t)gr * K + bcol, &Bs[0][BN * 32 + rb * 32]);
        dma16(Bl + (size_t)gr * K + bcol, &Bs[0][BN * 64 + rb * 32]);
    }
    if (nk > 1) {
#pragma unroll
        for (int i = 0; i < NF4; ++i)
            prefA[i] = *(const float4*)(X + (size_t)(bm + i * 32 + arow) * ldx
                                        + 32 + acol);
    }
#pragma unroll
    for (int i = 0; i < NF4; ++i) prefB[i] = prefA[i];
    __syncthreads();   // one-time full drain

    for (int t = 0; t < nk; ++t) {
        // ---- early issue: B(t+1) DMA + A(t+2) loads ----
        if (t + 1 < nk) {
            const int k0n = (t + 1) * 32;
            us16* BsN = Bs[(t + 1) & 1];
#pragma unroll
            for (int q = 0; q < LB; ++q) {
                const int rb = wid * (LB * 16) + q * 16;
                const int gr = bn + rb + (lane >> 2);
                dma16(Bh + (size_t)gr * K + k0n + bcol, &BsN[rb * 32]);
                dma16(Bm + (size_t)gr * K + k0n + bcol, &BsN[BN * 32 + rb * 32]);
                dma16(Bl + (size_t)gr * K + k0n + bcol, &BsN[BN * 64 + rb * 32]);
            }
            if (t + 2 < nk) {
#pragma unroll
                for (int i = 0; i < NF4; ++i)
                    prefB[i] = *(const float4*)(X + (size_t)(bm + i * 32 + arow) * ldx
                                                + (t + 2) * 32 + acol);
            }
        }

        // ---- compute tile t: 6 product tiers (hh, hm, mh, hl, mm, lh) ----
        const us16* BsC = Bs[t & 1];
        s16x8 ah[MT], am[MT], al[MT];
#pragma unroll
        for (int mt = 0; mt < MT; ++mt) {
            const int off = (wm + mt * 16 + lm) * 32 + (kb * 8 ^ fsw);
            ah[mt] = *(const s16x8*)&As[off];
            am[mt] = *(const s16x8*)&As[BM * 32 + off];
            al[mt] = *(const s16x8*)&As[BM * 64 + off];
        }
#pragma unroll
        for (int nt = 0; nt < NT; ++nt) {
            const int off = (wn + nt * 16 + lm) * 32 + (kb * 8 ^ fsw);
            s16x8 bfh = *(const s16x8*)&BsC[off];
            s16x8 bfm = *(const s16x8*)&BsC[BN * 32 + off];
            s16x8 bfl = *(const s16x8*)&BsC[BN * 64 + off];
#pragma unroll
            for (int mt = 0; mt < MT; ++mt) {
                acc[mt][nt] = mfma16(ah[mt], bfh, acc[mt][nt]);
                acc[mt][nt] = mfma16(ah[mt], bfm, acc[mt][nt]);
                acc[mt][nt] = mfma16(am[mt], bfh, acc[mt][nt]);
                acc[mt][nt] = mfma16(ah[mt], bfl, acc[mt][nt]);
                acc[mt][nt] = mfma16(am[mt], bfm, acc[mt][nt]);
                acc[mt][nt] = mfma16(al[mt], bfh, acc[mt][nt]);
            }
        }

        // ---- rotate A buffer for tile t+1 ----
        if (t + 1 < nk) {
            __syncthreads();   // all waves done reading As(t); drains hidden loads
#pragma unroll
            for (int i = 0; i < NF4; ++i) {
                const int r = i * 32 + arow;
                uint2 h, m, l;
                split4pk(prefA[i], h, m, l);
                *(uint2*)&As[r * 32 + (acol ^ asw)] = h;
                *(uint2*)&As[BM * 32 + r * 32 + (acol ^ asw)] = m;
                *(uint2*)&As[BM * 64 + r * 32 + (acol ^ asw)] = l;
            }
#pragma unroll
            for (int i = 0; i < NF4; ++i) prefA[i] = prefB[i];
            __syncthreads();   // As(t+1) visible
        }
    }

    // ---- epilogue: bias + activation (C/D map: col=lane&15, row=quad*4+r) ----
    float bv[NT];
#pragma unroll
    for (int nt = 0; nt < NT; ++nt) {
        const int col = bn + wn + nt * 16 + lm;
        bv[nt] = (col < nreal) ? bias[col] : 0.f;
    }
#pragma unroll
    for (int nt = 0; nt < NT; ++nt) {
        const int col = bn + wn + nt * 16 + lm;
#pragma unroll
        for (int mt = 0; mt < MT; ++mt) {
#pragma unroll
            for (int r = 0; r < 4; ++r) {
                const int row = bm + wm + mt * 16 + kb * 4 + r;
                float v = acc[mt][nt][r] + bv[nt];
                if (OUT == 0) {
                    C[(size_t)row * ldc + col] = fmaxf(v, 0.f);
                } else {
                    if (col < nreal)
                        C[(size_t)row * ldc + col] = tanhf(v);
                }
            }
        }
    }
}

// ---------------------------------------------------------------------------
// Weight pre-split into padded bf16 hi/mid/lo planes.
// Plane layout (ushort offsets): w1v [512x2048] @0, w1t @1048576, w1s @1114112,
// w2v @1179648, wfp [256x416 pad] @1245184, wfc [64x256 pad] @1351680; tot 1368064
// ---------------------------------------------------------------------------
#define WOFF_W1T 1048576
#define WOFF_W1S 1114112
#define WOFF_W2V 1179648
#define WOFF_WFP 1245184
#define WOFF_WFC 1351680
#define WTOT     1368064

__global__ void split_weights(const float* __restrict__ w1v, const float* __restrict__ w1t,
                              const float* __restrict__ w1s, const float* __restrict__ w2v,
                              const float* __restrict__ wfp, const float* __restrict__ wfc,
                              us16* __restrict__ hi, us16* __restrict__ mi,
                              us16* __restrict__ lo)
{
    int idx = blockIdx.x * 256 + threadIdx.x;
    if (idx >= WTOT) return;
    const float* src; int N, K, Kp; int local;
    if (idx < WOFF_W1T)      { src = w1v; N = 512; K = 2048; Kp = 2048; local = idx; }
    else if (idx < WOFF_W1S) { src = w1t; N = 128; K = 512;  Kp = 512;  local = idx - WOFF_W1T; }
    else if (idx < WOFF_W2V) { src = w1s; N = 128; K = 512;  Kp = 512;  local = idx - WOFF_W1S; }
    else if (idx < WOFF_WFP) { src = w2v; N = 128; K = 512;  Kp = 512;  local = idx - WOFF_W2V; }
    else if (idx < WOFF_WFC) { src = wfp; N = 256; K = 388;  Kp = 416;  local = idx - WOFF_WFP; }
    else                     { src = wfc; N = 36;  K = 256;  Kp = 256;  local = idx - WOFF_WFC; }
    int n = local / Kp, k = local % Kp;
    float v = (n < N && k < K) ? src[(size_t)n * K + k] : 0.f;
    us16 h, m, l;
    split3(v, h, m, l);
    hi[idx] = h; mi[idx] = m; lo[idx] = l;
}

// ---------------------------------------------------------------------------
// pos branch + cat K-padding: cat cols [256,260) = relu(pos), [388,416) = 0
// ---------------------------------------------------------------------------
__global__ void pos_pad(const float* __restrict__ seq, float* __restrict__ cat)
{
    int idx = blockIdx.x * 256 + threadIdx.x;
    if (idx >= MROWS * 32) return;
    int row = idx >> 5, j = idx & 31;
    if (j < 4) {
        float v = seq[(size_t)row * 3076 + 2560 + j];
        cat[(size_t)row * 416 + 256 + j] = fmaxf(v, 0.f);
    } else {
        cat[(size_t)row * 416 + 388 + (j - 4)] = 0.f;
    }
}

// ---------------------------------------------------------------------------
// Sinkhorn (verified in R2)
// ---------------------------------------------------------------------------
__global__ __launch_bounds__(256)
void sinkhorn_kernel(const float* __restrict__ Z, float* __restrict__ out)
{
    __shared__ float A[NMAT][NMAT + 1];
    __shared__ float lse[NMAT];
    const int b = blockIdx.x;
    const int tid = threadIdx.x;
    const float* zb = Z + (size_t)b * NMAT * NMAT;

    for (int idx = tid; idx < NMAT * NMAT; idx += 256)
        A[idx / NMAT][idx % NMAT] = expf(zb[idx] * TAU_INV);
    __syncthreads();

    for (int it = 0; it < 20; ++it) {
        if (tid < NMAT * 4) {
            int r = tid >> 2, g = tid & 3;
            float m = -3.402823466e38f;
            for (int j = g; j < NMAT; j += 4) m = fmaxf(m, A[r][j]);
            m = fmaxf(m, __shfl_xor(m, 2, 4));
            m = fmaxf(m, __shfl_xor(m, 1, 4));
            float s = 0.f;
            for (int j = g; j < NMAT; j += 4) s += expf(A[r][j] - m);
            s += __shfl_xor(s, 2, 4);
            s += __shfl_xor(s, 1, 4);
            if (g == 0) lse[r] = m + logf(s);
        }
        __syncthreads();
        for (int idx = tid; idx < NMAT * NMAT; idx += 256)
            A[idx / NMAT][idx % NMAT] -= lse[idx / NMAT];
        __syncthreads();

        if (tid < NMAT * 4) {
            int c = tid >> 2, g = tid & 3;
            float m = -3.402823466e38f;
            for (int i = g; i < NMAT; i += 4) m = fmaxf(m, A[i][c]);
            m = fmaxf(m, __shfl_xor(m, 2, 4));
            m = fmaxf(m, __shfl_xor(m, 1, 4));
            float s = 0.f;
            for (int i = g; i < NMAT; i += 4) s += expf(A[i][c] - m);
            s += __shfl_xor(s, 2, 4);
            s += __shfl_xor(s, 1, 4);
            if (g == 0) lse[c] = m + logf(s);
        }
        __syncthreads();
        for (int idx = tid; idx < NMAT * NMAT; idx += 256)
            A[idx / NMAT][idx % NMAT] -= lse[idx % NMAT];
        __syncthreads();
    }

    for (int idx = tid; idx < NMAT * NMAT; idx += 256)
        out[(size_t)b * NMAT * NMAT + idx] = expf(A[idx / NMAT][idx % NMAT]);
}

// ---------------------------------------------------------------------------
extern "C" void kernel_launch(void* const* d_in, const int* in_sizes, int n_in,
                              void* d_out, int out_size, void* d_ws, size_t ws_size,
                              hipStream_t stream)
{
    const float* seq = (const float*)d_in[0];
    const float* W1t = (const float*)d_in[1];
    const float* b1t = (const float*)d_in[2];
    const float* W1v = (const float*)d_in[3];
    const float* b1v = (const float*)d_in[4];
    const float* W2v = (const float*)d_in[5];
    const float* b2v = (const float*)d_in[6];
    const float* W1s = (const float*)d_in[7];
    const float* b1s = (const float*)d_in[8];
    const float* Wfp = (const float*)d_in[9];
    const float* bfp = (const float*)d_in[10];
    const float* Wfc = (const float*)d_in[11];
    const float* bfc = (const float*)d_in[12];

    float* wsF = (float*)d_ws;
    // ws layout (float offsets):
    //   [0, 4718592)        : vis1half (9216x512); later h256 (18432x256)
    //   [4718592, 12386304) : cat (18432x416); later logits (18432x36)
    //   [12386304, +2052096): weight planes hi/mid/lo (3 x WTOT ushorts)
    float* vis1buf = wsF;
    float* h256    = wsF;
    float* cat     = wsF + 4718592;
    float* logits  = wsF + 4718592;   // overlays cat (dead when fc runs)
    us16*  Whi     = (us16*)(wsF + 12386304);
    us16*  Wmi     = Whi + WTOT;
    us16*  Wlo     = Wmi + WTOT;

    dim3 blk(256);

    // 1. pre-split weights into padded bf16 planes
    split_weights<<<dim3((WTOT + 255) / 256), blk, 0, stream>>>(
        W1v, W1t, W1s, W2v, Wfp, Wfc, Whi, Wmi, Wlo);
    // 2. pos branch + cat pad cols
    pos_pad<<<dim3((MROWS * 32 + 255) / 256), blk, 0, stream>>>(seq, cat);
    // 3. txt: (M,512)->128 relu -> cat[:,0:128)
    gemm_split<64, 128, 0><<<dim3(MROWS / 64, 1), blk, 0, stream>>>(
        seq, 3076, Whi + WOFF_W1T, Wmi + WOFF_W1T, Wlo + WOFF_W1T, b1t,
        cat, 416, 128, 512);
    // 4. sen: (M,512)->128 relu -> cat[:,260:388)
    gemm_split<64, 128, 0><<<dim3(MROWS / 64, 1), blk, 0, stream>>>(
        seq + 2564, 3076, Whi + WOFF_W1S, Wmi + WOFF_W1S, Wlo + WOFF_W1S, b1s,
        cat + 260, 416, 128, 512);
    // 5-8. vis branch in two M-halves (ws capacity)
    for (int h = 0; h < 2; ++h) {
        const float* xh = seq + 512 + (size_t)h * MHALF * 3076;
        float* ch = cat + 128 + (size_t)h * MHALF * 416;
        gemm_split<64, 128, 0><<<dim3(MHALF / 64, 4), blk, 0, stream>>>(
            xh, 3076, Whi, Wmi, Wlo, b1v, vis1buf, 512, 512, 2048);
        gemm_split<64, 128, 0><<<dim3(MHALF / 64, 1), blk, 0, stream>>>(
            vis1buf, 512, Whi + WOFF_W2V, Wmi + WOFF_W2V, Wlo + WOFF_W2V, b2v,
            ch, 416, 128, 512);
    }
    // 9. fc_pos: (M,416)->256 relu -> h256 (overlays vis1buf, now dead)
    gemm_split<64, 128, 0><<<dim3(MROWS / 64, 2), blk, 0, stream>>>(
        cat, 416, Whi + WOFF_WFP, Wmi + WOFF_WFP, Wlo + WOFF_WFP, bfp,
        h256, 256, 256, 416);
    // 10. fc: (M,256)->36 tanh -> logits (overlays cat, now dead)
    gemm_split<64, 64, 1><<<dim3(MROWS / 64, 1), blk, 0, stream>>>(
        h256, 256, Whi + WOFF_WFC, Wmi + WOFF_WFC, Wlo + WOFF_WFC, bfc,
        logits, 36, 36, 256);
    // 11. sinkhorn
    sinkhorn_kernel<<<dim3(BATCH), blk, 0, stream>>>(logits, (float*)d_out);
}

// Round 5
// 701.722 us; speedup vs baseline: 1.2607x; 1.2607x over previous
//
#include <hip/hip_runtime.h>
#include <cstddef>
#include <cstdint>
#include <cmath>

#define TAU_INV 20.0f
#define NMAT 36
#define BATCH 512
#define MROWS 18432   // 512 * 36
#define MHALF 9216

typedef unsigned short us16;
typedef __attribute__((ext_vector_type(8))) short s16x8;   // 8 bf16 = 4 VGPRs
typedef __attribute__((ext_vector_type(4))) float f32x4;

// ---------------- bf16 helpers (RNE) ----------------
__device__ inline us16 f2bf(float x) {
    uint32_t u = __float_as_uint(x);
    u += 0x7fff + ((u >> 16) & 1);
    return (us16)(u >> 16);
}
__device__ inline float bf2f(us16 h) {
    return __uint_as_float(((uint32_t)h) << 16);
}
// 3-way split: x ~= h + m + l, residual <= 2^-27 |x| (scalar, weights only)
__device__ inline void split3(float v, us16& h, us16& m, us16& l) {
    h = f2bf(v);
    float r1 = v - bf2f(h);
    m = f2bf(r1);
    l = f2bf(r1 - bf2f(m));
}

// packed f32x2 -> bf16x2 convert (T12 recipe; no builtin on gfx950)
__device__ inline uint32_t cvtpk(float lo, float hi) {
    uint32_t d;
    asm("v_cvt_pk_bf16_f32 %0, %1, %2" : "=v"(d) : "v"(lo), "v"(hi));
    return d;
}
// split 4 floats into packed h/m/l bf16 plane words (residuals exact)
__device__ inline void split4pk(const float4& v, uint2& h, uint2& m, uint2& l) {
    uint32_t h0 = cvtpk(v.x, v.y), h1 = cvtpk(v.z, v.w);
    float a0 = v.x - __uint_as_float(h0 << 16);
    float a1 = v.y - __uint_as_float(h0 & 0xffff0000u);
    float a2 = v.z - __uint_as_float(h1 << 16);
    float a3 = v.w - __uint_as_float(h1 & 0xffff0000u);
    uint32_t m0 = cvtpk(a0, a1), m1 = cvtpk(a2, a3);
    a0 -= __uint_as_float(m0 << 16);
    a1 -= __uint_as_float(m0 & 0xffff0000u);
    a2 -= __uint_as_float(m1 << 16);
    a3 -= __uint_as_float(m1 & 0xffff0000u);
    uint32_t l0 = cvtpk(a0, a1), l1 = cvtpk(a2, a3);
    h = make_uint2(h0, h1); m = make_uint2(m0, m1); l = make_uint2(l0, l1);
}

// ---------------- async global->LDS 16B DMA ----------------
__device__ inline void dma16(const void* g, void* l) {
    __builtin_amdgcn_global_load_lds(
        (const __attribute__((address_space(1))) void*)g,
        (__attribute__((address_space(3))) void*)l, 16, 0, 0);
}

__device__ inline f32x4 mfma16(s16x8 a, s16x8 b, f32x4 c) {
    return __builtin_amdgcn_mfma_f32_16x16x32_bf16(a, b, c, 0, 0, 0);
}

// ---------------------------------------------------------------------------
// 3-way-split bf16 MFMA GEMM:  C = act(X @ W^T + bias)  (fp32-equivalent)
//   X: fp32 [M][ldx] (split on the fly, cvt_pk), W: pre-split bf16 planes.
// R3-proven 2-barrier k-loop (NO explicit pipeline — R4 showed it regresses;
// wave-level overlap via 4 blocks/CU does the hiding, m114). Single-buffered
// LDS: (BM+BN)*96 us16 = 36 KB at <64,128> -> 4 blocks/CU, 16 waves/CU.
// LDS swizzle (verified R3: SQ_LDS_BANK_CONFLICT = 0): us16 idx =
//   row*32 + ((slot8 ^ ((row>>1)&3))*8 + e); A swizzled write+read;
//   B linear DMA dest + pre-swizzled global source col + swizzled read.
// Dual-param-set: blockIdx.z==1 selects the second set (used to co-schedule
// txt+sen in one dispatch; pass duplicates for single-set launches).
// OUT: 0 = relu; 1 = tanh with col<nreal store guard.
// 256 threads = 4 waves, 2x2 wave grid; wave tile (BM/2)x(BN/2).
// ---------------------------------------------------------------------------
template<int BM, int BN, int OUT>
__global__ __launch_bounds__(256, 4)
void gemm_split(const float* X, int ldx,
                const us16* Bh, const us16* Bm, const us16* Bl,
                const float* bias, float* C, int ldc, int nreal, int K,
                const float* X2, const us16* Bh2, const us16* Bm2,
                const us16* Bl2, const float* bias2, float* C2)
{
    constexpr int MT  = BM / 32;      // 16-row m-tiles per wave
    constexpr int NT  = BN / 32;      // 16-col n-tiles per wave
    constexpr int NF4 = BM / 32;      // float4 A-loads per thread per k-tile
    constexpr int LB  = BN / 64;      // B DMA chunks per wave per plane

    if (blockIdx.z) { X = X2; Bh = Bh2; Bm = Bm2; Bl = Bl2; bias = bias2; C = C2; }

    alignas(16) __shared__ us16 lds[(BM + BN) * 96];
    us16* AsH = lds;
    us16* AsM = lds + BM * 32;
    us16* AsL = lds + BM * 64;
    us16* BsH = lds + BM * 96;
    us16* BsM = lds + BM * 96 + BN * 32;
    us16* BsL = lds + BM * 96 + BN * 64;

    const int tid  = threadIdx.x;
    const int lane = tid & 63;
    const int wid  = tid >> 6;
    const int bm   = blockIdx.x * BM;
    const int bn   = blockIdx.y * BN;
    const int lm   = lane & 15;       // fragment row/col within 16
    const int kb   = lane >> 4;       // k-quad 0..3
    const int wm   = (wid >> 1) * (BM / 2);
    const int wn   = (wid & 1) * (BN / 2);

    // A staging map: thread covers rows arow + i*32, cols acol..acol+3
    const int arow = tid >> 3;        // 0..31
    const int acol = (tid & 7) * 4;   // 0,4,..,28
    const int asw  = ((arow >> 1) & 3) << 3;   // A write swizzle (us16 idx bits 3-4)
    const int fsw  = ((lm >> 1) & 3) << 3;     // fragment read swizzle

    f32x4 acc[MT][NT];
#pragma unroll
    for (int i = 0; i < MT; ++i)
#pragma unroll
        for (int j = 0; j < NT; ++j) acc[i][j] = (f32x4){0.f, 0.f, 0.f, 0.f};

    float4 pref[NF4];
#pragma unroll
    for (int i = 0; i < NF4; ++i)
        pref[i] = *(const float4*)(X + (size_t)(bm + i * 32 + arow) * ldx + acol);

    // B DMA: linear dest (wave-uniform base + lane*16B), pre-swizzled src col
    const int bcol = ((lane & 3) ^ ((lane >> 3) & 3)) * 8;

    for (int k0 = 0; k0 < K; k0 += 32) {
        __syncthreads();   // previous compute done; LDS reusable
        // ---- split prefetched A into hi/mid/lo LDS planes (swizzled) ----
#pragma unroll
        for (int i = 0; i < NF4; ++i) {
            const int r = i * 32 + arow;
            uint2 h, m, l;
            split4pk(pref[i], h, m, l);
            *(uint2*)&AsH[r * 32 + (acol ^ asw)] = h;
            *(uint2*)&AsM[r * 32 + (acol ^ asw)] = m;
            *(uint2*)&AsL[r * 32 + (acol ^ asw)] = l;
        }
        // ---- async DMA B tile (3 planes), linear dest + pre-swizzled src ----
#pragma unroll
        for (int q = 0; q < LB; ++q) {
            const int rb = wid * (LB * 16) + q * 16;          // wave-uniform
            const int gr = bn + rb + (lane >> 2);
            const int gc = k0 + bcol;
            dma16(Bh + (size_t)gr * K + gc, &BsH[rb * 32]);
            dma16(Bm + (size_t)gr * K + gc, &BsM[rb * 32]);
            dma16(Bl + (size_t)gr * K + gc, &BsL[rb * 32]);
        }
        // ---- prefetch A for next k-tile ----
        if (k0 + 32 < K) {
#pragma unroll
            for (int i = 0; i < NF4; ++i)
                pref[i] = *(const float4*)(X + (size_t)(bm + i * 32 + arow) * ldx
                                           + (k0 + 32) + acol);
        }
        __syncthreads();   // staging visible (compiler drains vmcnt+lgkm)

        // ---- MFMA phase: 6 product tiers (hh, hm, mh, hl, mm, lh) ----
        s16x8 ah[MT], am[MT], al[MT];
#pragma unroll
        for (int mt = 0; mt < MT; ++mt) {
            const int off = (wm + mt * 16 + lm) * 32 + (kb * 8 ^ fsw);
            ah[mt] = *(const s16x8*)&AsH[off];
            am[mt] = *(const s16x8*)&AsM[off];
            al[mt] = *(const s16x8*)&AsL[off];
        }
#pragma unroll
        for (int nt = 0; nt < NT; ++nt) {
            const int off = (wn + nt * 16 + lm) * 32 + (kb * 8 ^ fsw);
            s16x8 bfh = *(const s16x8*)&BsH[off];
            s16x8 bfm = *(const s16x8*)&BsM[off];
            s16x8 bfl = *(const s16x8*)&BsL[off];
#pragma unroll
            for (int mt = 0; mt < MT; ++mt) {
                acc[mt][nt] = mfma16(ah[mt], bfh, acc[mt][nt]);
                acc[mt][nt] = mfma16(ah[mt], bfm, acc[mt][nt]);
                acc[mt][nt] = mfma16(am[mt], bfh, acc[mt][nt]);
                acc[mt][nt] = mfma16(ah[mt], bfl, acc[mt][nt]);
                acc[mt][nt] = mfma16(am[mt], bfm, acc[mt][nt]);
                acc[mt][nt] = mfma16(al[mt], bfh, acc[mt][nt]);
            }
        }
    }

    // ---- epilogue: bias + activation (C/D map: col=lane&15, row=quad*4+r) ----
    float bv[NT];
#pragma unroll
    for (int nt = 0; nt < NT; ++nt) {
        const int col = bn + wn + nt * 16 + lm;
        bv[nt] = (col < nreal) ? bias[col] : 0.f;
    }
#pragma unroll
    for (int nt = 0; nt < NT; ++nt) {
        const int col = bn + wn + nt * 16 + lm;
#pragma unroll
        for (int mt = 0; mt < MT; ++mt) {
#pragma unroll
            for (int r = 0; r < 4; ++r) {
                const int row = bm + wm + mt * 16 + kb * 4 + r;
                float v = acc[mt][nt][r] + bv[nt];
                if (OUT == 0) {
                    C[(size_t)row * ldc + col] = fmaxf(v, 0.f);
                } else {
                    if (col < nreal)
                        C[(size_t)row * ldc + col] = tanhf(v);
                }
            }
        }
    }
}

// ---------------------------------------------------------------------------
// Weight pre-split into padded bf16 hi/mid/lo planes.
// Plane layout (ushort offsets): w1v [512x2048] @0, w1t @1048576, w1s @1114112,
// w2v @1179648, wfp [256x416 pad] @1245184, wfc [64x256 pad] @1351680; tot 1368064
// ---------------------------------------------------------------------------
#define WOFF_W1T 1048576
#define WOFF_W1S 1114112
#define WOFF_W2V 1179648
#define WOFF_WFP 1245184
#define WOFF_WFC 1351680
#define WTOT     1368064

__global__ void split_weights(const float* __restrict__ w1v, const float* __restrict__ w1t,
                              const float* __restrict__ w1s, const float* __restrict__ w2v,
                              const float* __restrict__ wfp, const float* __restrict__ wfc,
                              us16* __restrict__ hi, us16* __restrict__ mi,
                              us16* __restrict__ lo)
{
    int idx = blockIdx.x * 256 + threadIdx.x;
    if (idx >= WTOT) return;
    const float* src; int N, K, Kp; int local;
    if (idx < WOFF_W1T)      { src = w1v; N = 512; K = 2048; Kp = 2048; local = idx; }
    else if (idx < WOFF_W1S) { src = w1t; N = 128; K = 512;  Kp = 512;  local = idx - WOFF_W1T; }
    else if (idx < WOFF_W2V) { src = w1s; N = 128; K = 512;  Kp = 512;  local = idx - WOFF_W1S; }
    else if (idx < WOFF_WFP) { src = w2v; N = 128; K = 512;  Kp = 512;  local = idx - WOFF_W2V; }
    else if (idx < WOFF_WFC) { src = wfp; N = 256; K = 388;  Kp = 416;  local = idx - WOFF_WFP; }
    else                     { src = wfc; N = 36;  K = 256;  Kp = 256;  local = idx - WOFF_WFC; }
    int n = local / Kp, k = local % Kp;
    float v = (n < N && k < K) ? src[(size_t)n * K + k] : 0.f;
    us16 h, m, l;
    split3(v, h, m, l);
    hi[idx] = h; mi[idx] = m; lo[idx] = l;
}

// ---------------------------------------------------------------------------
// pos branch + cat K-padding: cat cols [256,260) = relu(pos), [388,416) = 0
// ---------------------------------------------------------------------------
__global__ void pos_pad(const float* __restrict__ seq, float* __restrict__ cat)
{
    int idx = blockIdx.x * 256 + threadIdx.x;
    if (idx >= MROWS * 32) return;
    int row = idx >> 5, j = idx & 31;
    if (j < 4) {
        float v = seq[(size_t)row * 3076 + 2560 + j];
        cat[(size_t)row * 416 + 256 + j] = fmaxf(v, 0.f);
    } else {
        cat[(size_t)row * 416 + 388 + (j - 4)] = 0.f;
    }
}

// ---------------------------------------------------------------------------
// Sinkhorn (verified in R2)
// ---------------------------------------------------------------------------
__global__ __launch_bounds__(256)
void sinkhorn_kernel(const float* __restrict__ Z, float* __restrict__ out)
{
    __shared__ float A[NMAT][NMAT + 1];
    __shared__ float lse[NMAT];
    const int b = blockIdx.x;
    const int tid = threadIdx.x;
    const float* zb = Z + (size_t)b * NMAT * NMAT;

    for (int idx = tid; idx < NMAT * NMAT; idx += 256)
        A[idx / NMAT][idx % NMAT] = expf(zb[idx] * TAU_INV);
    __syncthreads();

    for (int it = 0; it < 20; ++it) {
        if (tid < NMAT * 4) {
            int r = tid >> 2, g = tid & 3;
            float m = -3.402823466e38f;
            for (int j = g; j < NMAT; j += 4) m = fmaxf(m, A[r][j]);
            m = fmaxf(m, __shfl_xor(m, 2, 4));
            m = fmaxf(m, __shfl_xor(m, 1, 4));
            float s = 0.f;
            for (int j = g; j < NMAT; j += 4) s += expf(A[r][j] - m);
            s += __shfl_xor(s, 2, 4);
            s += __shfl_xor(s, 1, 4);
            if (g == 0) lse[r] = m + logf(s);
        }
        __syncthreads();
        for (int idx = tid; idx < NMAT * NMAT; idx += 256)
            A[idx / NMAT][idx % NMAT] -= lse[idx / NMAT];
        __syncthreads();

        if (tid < NMAT * 4) {
            int c = tid >> 2, g = tid & 3;
            float m = -3.402823466e38f;
            for (int i = g; i < NMAT; i += 4) m = fmaxf(m, A[i][c]);
            m = fmaxf(m, __shfl_xor(m, 2, 4));
            m = fmaxf(m, __shfl_xor(m, 1, 4));
            float s = 0.f;
            for (int i = g; i < NMAT; i += 4) s += expf(A[i][c] - m);
            s += __shfl_xor(s, 2, 4);
            s += __shfl_xor(s, 1, 4);
            if (g == 0) lse[c] = m + logf(s);
        }
        __syncthreads();
        for (int idx = tid; idx < NMAT * NMAT; idx += 256)
            A[idx / NMAT][idx % NMAT] -= lse[idx % NMAT];
        __syncthreads();
    }

    for (int idx = tid; idx < NMAT * NMAT; idx += 256)
        out[(size_t)b * NMAT * NMAT + idx] = expf(A[idx / NMAT][idx % NMAT]);
}

// ---------------------------------------------------------------------------
extern "C" void kernel_launch(void* const* d_in, const int* in_sizes, int n_in,
                              void* d_out, int out_size, void* d_ws, size_t ws_size,
                              hipStream_t stream)
{
    const float* seq = (const float*)d_in[0];
    const float* W1t = (const float*)d_in[1];
    const float* b1t = (const float*)d_in[2];
    const float* W1v = (const float*)d_in[3];
    const float* b1v = (const float*)d_in[4];
    const float* W2v = (const float*)d_in[5];
    const float* b2v = (const float*)d_in[6];
    const float* W1s = (const float*)d_in[7];
    const float* b1s = (const float*)d_in[8];
    const float* Wfp = (const float*)d_in[9];
    const float* bfp = (const float*)d_in[10];
    const float* Wfc = (const float*)d_in[11];
    const float* bfc = (const float*)d_in[12];

    float* wsF = (float*)d_ws;
    // ws layout (float offsets):
    //   [0, 4718592)        : vis1half (9216x512); later h256 (18432x256)
    //   [4718592, 12386304) : cat (18432x416); later logits (18432x36)
    //   [12386304, +2052096): weight planes hi/mid/lo (3 x WTOT ushorts)
    float* vis1buf = wsF;
    float* h256    = wsF;
    float* cat     = wsF + 4718592;
    float* logits  = wsF + 4718592;   // overlays cat (dead when fc runs)
    us16*  Whi     = (us16*)(wsF + 12386304);
    us16*  Wmi     = Whi + WTOT;
    us16*  Wlo     = Wmi + WTOT;

    dim3 blk(256);

    // 1. pre-split weights into padded bf16 planes
    split_weights<<<dim3((WTOT + 255) / 256), blk, 0, stream>>>(
        W1v, W1t, W1s, W2v, Wfp, Wfc, Whi, Wmi, Wlo);
    // 2. pos branch + cat pad cols
    pos_pad<<<dim3((MROWS * 32 + 255) / 256), blk, 0, stream>>>(seq, cat);
    // 3+4. txt & sen fused in one dispatch (blockIdx.z selects param set):
    //      txt: (M,512)->128 relu -> cat[:,0:128)
    //      sen: (M,512)->128 relu -> cat[:,260:388)
    gemm_split<64, 128, 0><<<dim3(MROWS / 64, 1, 2), blk, 0, stream>>>(
        seq, 3076, Whi + WOFF_W1T, Wmi + WOFF_W1T, Wlo + WOFF_W1T, b1t,
        cat, 416, 128, 512,
        seq + 2564, Whi + WOFF_W1S, Wmi + WOFF_W1S, Wlo + WOFF_W1S, b1s,
        cat + 260);
    // 5-8. vis branch in two M-halves (ws capacity)
    for (int h = 0; h < 2; ++h) {
        const float* xh = seq + 512 + (size_t)h * MHALF * 3076;
        float* ch = cat + 128 + (size_t)h * MHALF * 416;
        gemm_split<64, 128, 0><<<dim3(MHALF / 64, 4, 1), blk, 0, stream>>>(
            xh, 3076, Whi, Wmi, Wlo, b1v, vis1buf, 512, 512, 2048,
            xh, Whi, Wmi, Wlo, b1v, vis1buf);
        gemm_split<64, 128, 0><<<dim3(MHALF / 64, 1, 1), blk, 0, stream>>>(
            vis1buf, 512, Whi + WOFF_W2V, Wmi + WOFF_W2V, Wlo + WOFF_W2V, b2v,
            ch, 416, 128, 512,
            vis1buf, Whi + WOFF_W2V, Wmi + WOFF_W2V, Wlo + WOFF_W2V, b2v, ch);
    }
    // 9. fc_pos: (M,416)->256 relu -> h256 (overlays vis1buf, now dead)
    gemm_split<64, 128, 0><<<dim3(MROWS / 64, 2, 1), blk, 0, stream>>>(
        cat, 416, Whi + WOFF_WFP, Wmi + WOFF_WFP, Wlo + WOFF_WFP, bfp,
        h256, 256, 256, 416,
        cat, Whi + WOFF_WFP, Wmi + WOFF_WFP, Wlo + WOFF_WFP, bfp, h256);
    // 10. fc: (M,256)->36 tanh -> logits (overlays cat, now dead)
    gemm_split<64, 64, 1><<<dim3(MROWS / 64, 1, 1), blk, 0, stream>>>(
        h256, 256, Whi + WOFF_WFC, Wmi + WOFF_WFC, Wlo + WOFF_WFC, bfc,
        logits, 36, 36, 256,
        h256, Whi + WOFF_WFC, Wmi + WOFF_WFC, Wlo + WOFF_WFC, bfc, logits);
    // 11. sinkhorn
    sinkhorn_kernel<<<dim3(BATCH), blk, 0, stream>>>(logits, (float*)d_out);
}

// Round 9
// 680.260 us; speedup vs baseline: 1.3005x; 1.0315x over previous
//
#include <hip/hip_runtime.h>
#include <cstddef>
#include <cstdint>
#include <cmath>

#define TAU_INV 20.0f
#define NMAT 36
#define BATCH 512
#define MROWS 18432   // 512 * 36
#define MHALF 9216

typedef unsigned short us16;
typedef __attribute__((ext_vector_type(8))) short s16x8;   // 8 bf16 = 4 VGPRs
typedef __attribute__((ext_vector_type(4))) float f32x4;

// ---------------- bf16 helpers (RNE) ----------------
__device__ inline us16 f2bf(float x) {
    uint32_t u = __float_as_uint(x);
    u += 0x7fff + ((u >> 16) & 1);
    return (us16)(u >> 16);
}
__device__ inline float bf2f(us16 h) {
    return __uint_as_float(((uint32_t)h) << 16);
}
// 3-way split: x ~= h + m + l, residual <= 2^-27 |x| (scalar, weights only)
__device__ inline void split3(float v, us16& h, us16& m, us16& l) {
    h = f2bf(v);
    float r1 = v - bf2f(h);
    m = f2bf(r1);
    l = f2bf(r1 - bf2f(m));
}

// packed f32x2 -> bf16x2 convert (T12 recipe; no builtin on gfx950)
__device__ inline uint32_t cvtpk(float lo, float hi) {
    uint32_t d;
    asm("v_cvt_pk_bf16_f32 %0, %1, %2" : "=v"(d) : "v"(lo), "v"(hi));
    return d;
}
// split 4 floats into packed h/m/l bf16 plane words (residuals exact)
__device__ inline void split4pk(const float4& v, uint2& h, uint2& m, uint2& l) {
    uint32_t h0 = cvtpk(v.x, v.y), h1 = cvtpk(v.z, v.w);
    float a0 = v.x - __uint_as_float(h0 << 16);
    float a1 = v.y - __uint_as_float(h0 & 0xffff0000u);
    float a2 = v.z - __uint_as_float(h1 << 16);
    float a3 = v.w - __uint_as_float(h1 & 0xffff0000u);
    uint32_t m0 = cvtpk(a0, a1), m1 = cvtpk(a2, a3);
    a0 -= __uint_as_float(m0 << 16);
    a1 -= __uint_as_float(m0 & 0xffff0000u);
    a2 -= __uint_as_float(m1 << 16);
    a3 -= __uint_as_float(m1 & 0xffff0000u);
    uint32_t l0 = cvtpk(a0, a1), l1 = cvtpk(a2, a3);
    h = make_uint2(h0, h1); m = make_uint2(m0, m1); l = make_uint2(l0, l1);
}

// ---------------- async global->LDS 16B DMA ----------------
__device__ inline void dma16(const void* g, void* l) {
    __builtin_amdgcn_global_load_lds(
        (const __attribute__((address_space(1))) void*)g,
        (__attribute__((address_space(3))) void*)l, 16, 0, 0);
}

__device__ inline f32x4 mfma16(s16x8 a, s16x8 b, f32x4 c) {
    return __builtin_amdgcn_mfma_f32_16x16x32_bf16(a, b, c, 0, 0, 0);
}

// ---------------------------------------------------------------------------
// 3-way-split bf16 MFMA GEMM:  C = act(X @ W^T + bias)  (fp32-equivalent)
//   X: fp32 [M][ldx] (split on the fly, cvt_pk), W: pre-split bf16 planes.
// R3/R5-proven 2-barrier k-loop (explicit pipelining regresses, R4; the
// hiding comes from 4 blocks/CU wave-level overlap, m114). Single-buffered
// LDS: (BM+BN)*96 us16 = 36 KB at <64,128> -> 4 blocks/CU, 16 waves/CU.
// LDS swizzle (verified R3: SQ_LDS_BANK_CONFLICT = 0): us16 idx =
//   row*32 + ((slot8 ^ ((row>>1)&3))*8 + e); A swizzled write+read;
//   B linear DMA dest + pre-swizzled global source col + swizzled read.
// Dual-param-set: blockIdx.z==1 selects the second set (co-schedules txt+sen
// in one dispatch; pass duplicates for single-set launches).
// OUT: 0 = relu; 1 = tanh with col<nreal store guard.
// 256 threads = 4 waves, 2x2 wave grid; wave tile (BM/2)x(BN/2).
// ---------------------------------------------------------------------------
template<int BM, int BN, int OUT>
__global__ __launch_bounds__(256, 4)
void gemm_split(const float* X, int ldx,
                const us16* Bh, const us16* Bm, const us16* Bl,
                const float* bias, float* C, int ldc, int nreal, int K,
                const float* X2, const us16* Bh2, const us16* Bm2,
                const us16* Bl2, const float* bias2, float* C2)
{
    constexpr int MT  = BM / 32;      // 16-row m-tiles per wave
    constexpr int NT  = BN / 32;      // 16-col n-tiles per wave
    constexpr int NF4 = BM / 32;      // float4 A-loads per thread per k-tile
    constexpr int LB  = BN / 64;      // B DMA chunks per wave per plane

    if (blockIdx.z) { X = X2; Bh = Bh2; Bm = Bm2; Bl = Bl2; bias = bias2; C = C2; }

    alignas(16) __shared__ us16 lds[(BM + BN) * 96];
    us16* AsH = lds;
    us16* AsM = lds + BM * 32;
    us16* AsL = lds + BM * 64;
    us16* BsH = lds + BM * 96;
    us16* BsM = lds + BM * 96 + BN * 32;
    us16* BsL = lds + BM * 96 + BN * 64;

    const int tid  = threadIdx.x;
    const int lane = tid & 63;
    const int wid  = tid >> 6;
    const int bm   = blockIdx.x * BM;
    const int bn   = blockIdx.y * BN;
    const int lm   = lane & 15;       // fragment row/col within 16
    const int kb   = lane >> 4;       // k-quad 0..3
    const int wm   = (wid >> 1) * (BM / 2);
    const int wn   = (wid & 1) * (BN / 2);

    // A staging map: thread covers rows arow + i*32, cols acol..acol+3
    const int arow = tid >> 3;        // 0..31
    const int acol = (tid & 7) * 4;   // 0,4,..,28
    const int asw  = ((arow >> 1) & 3) << 3;   // A write swizzle (us16 idx bits 3-4)
    const int fsw  = ((lm >> 1) & 3) << 3;     // fragment read swizzle

    f32x4 acc[MT][NT];
#pragma unroll
    for (int i = 0; i < MT; ++i)
#pragma unroll
        for (int j = 0; j < NT; ++j) acc[i][j] = (f32x4){0.f, 0.f, 0.f, 0.f};

    float4 pref[NF4];
#pragma unroll
    for (int i = 0; i < NF4; ++i)
        pref[i] = *(const float4*)(X + (size_t)(bm + i * 32 + arow) * ldx + acol);

    // B DMA: linear dest (wave-uniform base + lane*16B), pre-swizzled src col
    const int bcol = ((lane & 3) ^ ((lane >> 3) & 3)) * 8;

    for (int k0 = 0; k0 < K; k0 += 32) {
        __syncthreads();   // previous compute done; LDS reusable
        // ---- split prefetched A into hi/mid/lo LDS planes (swizzled) ----
#pragma unroll
        for (int i = 0; i < NF4; ++i) {
            const int r = i * 32 + arow;
            uint2 h, m, l;
            split4pk(pref[i], h, m, l);
            *(uint2*)&AsH[r * 32 + (acol ^ asw)] = h;
            *(uint2*)&AsM[r * 32 + (acol ^ asw)] = m;
            *(uint2*)&AsL[r * 32 + (acol ^ asw)] = l;
        }
        // ---- async DMA B tile (3 planes), linear dest + pre-swizzled src ----
#pragma unroll
        for (int q = 0; q < LB; ++q) {
            const int rb = wid * (LB * 16) + q * 16;          // wave-uniform
            const int gr = bn + rb + (lane >> 2);
            const int gc = k0 + bcol;
            dma16(Bh + (size_t)gr * K + gc, &BsH[rb * 32]);
            dma16(Bm + (size_t)gr * K + gc, &BsM[rb * 32]);
            dma16(Bl + (size_t)gr * K + gc, &BsL[rb * 32]);
        }
        // ---- prefetch A for next k-tile ----
        if (k0 + 32 < K) {
#pragma unroll
            for (int i = 0; i < NF4; ++i)
                pref[i] = *(const float4*)(X + (size_t)(bm + i * 32 + arow) * ldx
                                           + (k0 + 32) + acol);
        }
        __syncthreads();   // staging visible (compiler drains vmcnt+lgkm)

        // ---- MFMA phase: 6 product tiers (hh, hm, mh, hl, mm, lh) ----
        s16x8 ah[MT], am[MT], al[MT];
#pragma unroll
        for (int mt = 0; mt < MT; ++mt) {
            const int off = (wm + mt * 16 + lm) * 32 + (kb * 8 ^ fsw);
            ah[mt] = *(const s16x8*)&AsH[off];
            am[mt] = *(const s16x8*)&AsM[off];
            al[mt] = *(const s16x8*)&AsL[off];
        }
#pragma unroll
        for (int nt = 0; nt < NT; ++nt) {
            const int off = (wn + nt * 16 + lm) * 32 + (kb * 8 ^ fsw);
            s16x8 bfh = *(const s16x8*)&BsH[off];
            s16x8 bfm = *(const s16x8*)&BsM[off];
            s16x8 bfl = *(const s16x8*)&BsL[off];
#pragma unroll
            for (int mt = 0; mt < MT; ++mt) {
                acc[mt][nt] = mfma16(ah[mt], bfh, acc[mt][nt]);
                acc[mt][nt] = mfma16(ah[mt], bfm, acc[mt][nt]);
                acc[mt][nt] = mfma16(am[mt], bfh, acc[mt][nt]);
                acc[mt][nt] = mfma16(ah[mt], bfl, acc[mt][nt]);
                acc[mt][nt] = mfma16(am[mt], bfm, acc[mt][nt]);
                acc[mt][nt] = mfma16(al[mt], bfh, acc[mt][nt]);
            }
        }
    }

    // ---- epilogue: bias + activation (C/D map: col=lane&15, row=quad*4+r) ----
    float bv[NT];
#pragma unroll
    for (int nt = 0; nt < NT; ++nt) {
        const int col = bn + wn + nt * 16 + lm;
        bv[nt] = (col < nreal) ? bias[col] : 0.f;
    }
#pragma unroll
    for (int nt = 0; nt < NT; ++nt) {
        const int col = bn + wn + nt * 16 + lm;
#pragma unroll
        for (int mt = 0; mt < MT; ++mt) {
#pragma unroll
            for (int r = 0; r < 4; ++r) {
                const int row = bm + wm + mt * 16 + kb * 4 + r;
                float v = acc[mt][nt][r] + bv[nt];
                if (OUT == 0) {
                    C[(size_t)row * ldc + col] = fmaxf(v, 0.f);
                } else {
                    if (col < nreal)
                        C[(size_t)row * ldc + col] = tanhf(v);
                }
            }
        }
    }
}

// ---------------------------------------------------------------------------
// Weight pre-split into padded bf16 hi/mid/lo planes.
// Plane layout (ushort offsets): w1v [512x2048] @0, w1t @1048576, w1s @1114112,
// w2v @1179648, wfp [256x416 pad] @1245184, wfc [64x256 pad] @1351680; tot 1368064
// ---------------------------------------------------------------------------
#define WOFF_W1T 1048576
#define WOFF_W1S 1114112
#define WOFF_W2V 1179648
#define WOFF_WFP 1245184
#define WOFF_WFC 1351680
#define WTOT     1368064

__global__ void split_weights(const float* __restrict__ w1v, const float* __restrict__ w1t,
                              const float* __restrict__ w1s, const float* __restrict__ w2v,
                              const float* __restrict__ wfp, const float* __restrict__ wfc,
                              us16* __restrict__ hi, us16* __restrict__ mi,
                              us16* __restrict__ lo)
{
    int idx = blockIdx.x * 256 + threadIdx.x;
    if (idx >= WTOT) return;
    const float* src; int N, K, Kp; int local;
    if (idx < WOFF_W1T)      { src = w1v; N = 512; K = 2048; Kp = 2048; local = idx; }
    else if (idx < WOFF_W1S) { src = w1t; N = 128; K = 512;  Kp = 512;  local = idx - WOFF_W1T; }
    else if (idx < WOFF_W2V) { src = w1s; N = 128; K = 512;  Kp = 512;  local = idx - WOFF_W1S; }
    else if (idx < WOFF_WFP) { src = w2v; N = 128; K = 512;  Kp = 512;  local = idx - WOFF_W2V; }
    else if (idx < WOFF_WFC) { src = wfp; N = 256; K = 388;  Kp = 416;  local = idx - WOFF_WFP; }
    else                     { src = wfc; N = 36;  K = 256;  Kp = 256;  local = idx - WOFF_WFC; }
    int n = local / Kp, k = local % Kp;
    float v = (n < N && k < K) ? src[(size_t)n * K + k] : 0.f;
    us16 h, m, l;
    split3(v, h, m, l);
    hi[idx] = h; mi[idx] = m; lo[idx] = l;
}

// ---------------------------------------------------------------------------
// pos branch + cat K-padding: cat cols [256,260) = relu(pos), [388,416) = 0
// ---------------------------------------------------------------------------
__global__ void pos_pad(const float* __restrict__ seq, float* __restrict__ cat)
{
    int idx = blockIdx.x * 256 + threadIdx.x;
    if (idx >= MROWS * 32) return;
    int row = idx >> 5, j = idx & 31;
    if (j < 4) {
        float v = seq[(size_t)row * 3076 + 2560 + j];
        cat[(size_t)row * 416 + 256 + j] = fmaxf(v, 0.f);
    } else {
        cat[(size_t)row * 416 + 388 + (j - 4)] = 0.f;
    }
}

// ---------------------------------------------------------------------------
// Sinkhorn (verified in R2)
// ---------------------------------------------------------------------------
__global__ __launch_bounds__(256)
void sinkhorn_kernel(const float* __restrict__ Z, float* __restrict__ out)
{
    __shared__ float A[NMAT][NMAT + 1];
    __shared__ float lse[NMAT];
    const int b = blockIdx.x;
    const int tid = threadIdx.x;
    const float* zb = Z + (size_t)b * NMAT * NMAT;

    for (int idx = tid; idx < NMAT * NMAT; idx += 256)
        A[idx / NMAT][idx % NMAT] = expf(zb[idx] * TAU_INV);
    __syncthreads();

    for (int it = 0; it < 20; ++it) {
        if (tid < NMAT * 4) {
            int r = tid >> 2, g = tid & 3;
            float m = -3.402823466e38f;
            for (int j = g; j < NMAT; j += 4) m = fmaxf(m, A[r][j]);
            m = fmaxf(m, __shfl_xor(m, 2, 4));
            m = fmaxf(m, __shfl_xor(m, 1, 4));
            float s = 0.f;
            for (int j = g; j < NMAT; j += 4) s += expf(A[r][j] - m);
            s += __shfl_xor(s, 2, 4);
            s += __shfl_xor(s, 1, 4);
            if (g == 0) lse[r] = m + logf(s);
        }
        __syncthreads();
        for (int idx = tid; idx < NMAT * NMAT; idx += 256)
            A[idx / NMAT][idx % NMAT] -= lse[idx / NMAT];
        __syncthreads();

        if (tid < NMAT * 4) {
            int c = tid >> 2, g = tid & 3;
            float m = -3.402823466e38f;
            for (int i = g; i < NMAT; i += 4) m = fmaxf(m, A[i][c]);
            m = fmaxf(m, __shfl_xor(m, 2, 4));
            m = fmaxf(m, __shfl_xor(m, 1, 4));
            float s = 0.f;
            for (int i = g; i < NMAT; i += 4) s += expf(A[i][c] - m);
            s += __shfl_xor(s, 2, 4);
            s += __shfl_xor(s, 1, 4);
            if (g == 0) lse[c] = m + logf(s);
        }
        __syncthreads();
        for (int idx = tid; idx < NMAT * NMAT; idx += 256)
            A[idx / NMAT][idx % NMAT] -= lse[idx % NMAT];
        __syncthreads();
    }

    for (int idx = tid; idx < NMAT * NMAT; idx += 256)
        out[(size_t)b * NMAT * NMAT + idx] = expf(A[idx / NMAT][idx % NMAT]);
}

// ---------------------------------------------------------------------------
extern "C" void kernel_launch(void* const* d_in, const int* in_sizes, int n_in,
                              void* d_out, int out_size, void* d_ws, size_t ws_size,
                              hipStream_t stream)
{
    const float* seq = (const float*)d_in[0];
    const float* W1t = (const float*)d_in[1];
    const float* b1t = (const float*)d_in[2];
    const float* W1v = (const float*)d_in[3];
    const float* b1v = (const float*)d_in[4];
    const float* W2v = (const float*)d_in[5];
    const float* b2v = (const float*)d_in[6];
    const float* W1s = (const float*)d_in[7];
    const float* b1s = (const float*)d_in[8];
    const float* Wfp = (const float*)d_in[9];
    const float* bfp = (const float*)d_in[10];
    const float* Wfc = (const float*)d_in[11];
    const float* bfc = (const float*)d_in[12];

    float* wsF = (float*)d_ws;
    dim3 blk(256);

    // Full-M layout needs 76.63 MB; R5 profile showed the harness poisons a
    // ~907 MB workspace, so this should always hold — but guard and fall
    // back to the proven 57.8 MB half-M path if not.
    const bool full = ws_size >= (size_t)19156992 * 4;

    if (full) {
        // ws layout (float offsets), full-M:
        //   [0, 9437184)         : vis1 (18432x512); later h256 (18432x256)
        //   [9437184, 17104896)  : cat (18432x416); later logits
        //   [17104896, +2052096) : weight planes hi/mid/lo (3 x WTOT us16)
        float* vis1buf = wsF;
        float* h256    = wsF;
        float* cat     = wsF + 9437184;
        float* logits  = wsF + 9437184;
        us16*  Whi     = (us16*)(wsF + 17104896);
        us16*  Wmi     = Whi + WTOT;
        us16*  Wlo     = Wmi + WTOT;

        split_weights<<<dim3((WTOT + 255) / 256), blk, 0, stream>>>(
            W1v, W1t, W1s, W2v, Wfp, Wfc, Whi, Wmi, Wlo);
        pos_pad<<<dim3((MROWS * 32 + 255) / 256), blk, 0, stream>>>(seq, cat);
        // txt & sen fused (blockIdx.z selects param set)
        gemm_split<64, 128, 0><<<dim3(MROWS / 64, 1, 2), blk, 0, stream>>>(
            seq, 3076, Whi + WOFF_W1T, Wmi + WOFF_W1T, Wlo + WOFF_W1T, b1t,
            cat, 416, 128, 512,
            seq + 2564, Whi + WOFF_W1S, Wmi + WOFF_W1S, Wlo + WOFF_W1S, b1s,
            cat + 260);
        // vis1 full-M: 288x4 = 1152 blocks -> 4.5 blocks/CU
        gemm_split<64, 128, 0><<<dim3(MROWS / 64, 4, 1), blk, 0, stream>>>(
            seq + 512, 3076, Whi, Wmi, Wlo, b1v, vis1buf, 512, 512, 2048,
            seq + 512, Whi, Wmi, Wlo, b1v, vis1buf);
        // vis2 full-M: BN=64, y=2 -> 576 blocks (24 KB LDS)
        gemm_split<64, 64, 0><<<dim3(MROWS / 64, 2, 1), blk, 0, stream>>>(
            vis1buf, 512, Whi + WOFF_W2V, Wmi + WOFF_W2V, Wlo + WOFF_W2V, b2v,
            cat + 128, 416, 128, 512,
            vis1buf, Whi + WOFF_W2V, Wmi + WOFF_W2V, Wlo + WOFF_W2V, b2v,
            cat + 128);
        // fc_pos: (M,416)->256 relu -> h256 (overlays vis1buf, now dead)
        gemm_split<64, 128, 0><<<dim3(MROWS / 64, 2, 1), blk, 0, stream>>>(
            cat, 416, Whi + WOFF_WFP, Wmi + WOFF_WFP, Wlo + WOFF_WFP, bfp,
            h256, 256, 256, 416,
            cat, Whi + WOFF_WFP, Wmi + WOFF_WFP, Wlo + WOFF_WFP, bfp, h256);
        // fc: (M,256)->36 tanh -> logits (overlays cat, now dead)
        gemm_split<64, 64, 1><<<dim3(MROWS / 64, 1, 1), blk, 0, stream>>>(
            h256, 256, Whi + WOFF_WFC, Wmi + WOFF_WFC, Wlo + WOFF_WFC, bfc,
            logits, 36, 36, 256,
            h256, Whi + WOFF_WFC, Wmi + WOFF_WFC, Wlo + WOFF_WFC, bfc, logits);
        sinkhorn_kernel<<<dim3(BATCH), blk, 0, stream>>>(logits, (float*)d_out);
    } else {
        // ---- R5-proven half-M fallback (57.8 MB) ----
        float* vis1buf = wsF;
        float* h256    = wsF;
        float* cat     = wsF + 4718592;
        float* logits  = wsF + 4718592;
        us16*  Whi     = (us16*)(wsF + 12386304);
        us16*  Wmi     = Whi + WTOT;
        us16*  Wlo     = Wmi + WTOT;

        split_weights<<<dim3((WTOT + 255) / 256), blk, 0, stream>>>(
            W1v, W1t, W1s, W2v, Wfp, Wfc, Whi, Wmi, Wlo);
        pos_pad<<<dim3((MROWS * 32 + 255) / 256), blk, 0, stream>>>(seq, cat);
        gemm_split<64, 128, 0><<<dim3(MROWS / 64, 1, 2), blk, 0, stream>>>(
            seq, 3076, Whi + WOFF_W1T, Wmi + WOFF_W1T, Wlo + WOFF_W1T, b1t,
            cat, 416, 128, 512,
            seq + 2564, Whi + WOFF_W1S, Wmi + WOFF_W1S, Wlo + WOFF_W1S, b1s,
            cat + 260);
        for (int h = 0; h < 2; ++h) {
            const float* xh = seq + 512 + (size_t)h * MHALF * 3076;
            float* ch = cat + 128 + (size_t)h * MHALF * 416;
            gemm_split<64, 128, 0><<<dim3(MHALF / 64, 4, 1), blk, 0, stream>>>(
                xh, 3076, Whi, Wmi, Wlo, b1v, vis1buf, 512, 512, 2048,
                xh, Whi, Wmi, Wlo, b1v, vis1buf);
            gemm_split<64, 128, 0><<<dim3(MHALF / 64, 1, 1), blk, 0, stream>>>(
                vis1buf, 512, Whi + WOFF_W2V, Wmi + WOFF_W2V, Wlo + WOFF_W2V, b2v,
                ch, 416, 128, 512,
                vis1buf, Whi + WOFF_W2V, Wmi + WOFF_W2V, Wlo + WOFF_W2V, b2v, ch);
        }
        gemm_split<64, 128, 0><<<dim3(MROWS / 64, 2, 1), blk, 0, stream>>>(
            cat, 416, Whi + WOFF_WFP, Wmi + WOFF_WFP, Wlo + WOFF_WFP, bfp,
            h256, 256, 256, 416,
            cat, Whi + WOFF_WFP, Wmi + WOFF_WFP, Wlo + WOFF_WFP, bfp, h256);
        gemm_split<64, 64, 1><<<dim3(MROWS / 64, 1, 1), blk, 0, stream>>>(
            h256, 256, Whi + WOFF_WFC, Wmi + WOFF_WFC, Wlo + WOFF_WFC, bfc,
            logits, 36, 36, 256,
            h256, Whi + WOFF_WFC, Wmi + WOFF_WFC, Wlo + WOFF_WFC, bfc, logits);
        sinkhorn_kernel<<<dim3(BATCH), blk, 0, stream>>>(logits, (float*)d_out);
    }
}

// Round 10
// 657.075 us; speedup vs baseline: 1.3463x; 1.0353x over previous
//
#include <hip/hip_runtime.h>
#include <cstddef>
#include <cstdint>
#include <cmath>

#define TAU_INV 20.0f
#define NMAT 36
#define BATCH 512
#define MROWS 18432   // 512 * 36
#define MHALF 9216

typedef unsigned short us16;
typedef __attribute__((ext_vector_type(8))) short s16x8;   // 8 bf16 = 4 VGPRs
typedef __attribute__((ext_vector_type(4))) float f32x4;

// ---------------- bf16 helpers (RNE) ----------------
__device__ inline us16 f2bf(float x) {
    uint32_t u = __float_as_uint(x);
    u += 0x7fff + ((u >> 16) & 1);
    return (us16)(u >> 16);
}
__device__ inline float bf2f(us16 h) {
    return __uint_as_float(((uint32_t)h) << 16);
}
// 3-way split: x ~= h + m + l, residual <= 2^-27 |x| (scalar, weights only)
__device__ inline void split3(float v, us16& h, us16& m, us16& l) {
    h = f2bf(v);
    float r1 = v - bf2f(h);
    m = f2bf(r1);
    l = f2bf(r1 - bf2f(m));
}

// packed f32x2 -> bf16x2 convert (T12 recipe; no builtin on gfx950)
__device__ inline uint32_t cvtpk(float lo, float hi) {
    uint32_t d;
    asm("v_cvt_pk_bf16_f32 %0, %1, %2" : "=v"(d) : "v"(lo), "v"(hi));
    return d;
}
// split 4 floats into packed h/m/l bf16 plane words (residuals exact)
__device__ inline void split4pk(const float4& v, uint2& h, uint2& m, uint2& l) {
    uint32_t h0 = cvtpk(v.x, v.y), h1 = cvtpk(v.z, v.w);
    float a0 = v.x - __uint_as_float(h0 << 16);
    float a1 = v.y - __uint_as_float(h0 & 0xffff0000u);
    float a2 = v.z - __uint_as_float(h1 << 16);
    float a3 = v.w - __uint_as_float(h1 & 0xffff0000u);
    uint32_t m0 = cvtpk(a0, a1), m1 = cvtpk(a2, a3);
    a0 -= __uint_as_float(m0 << 16);
    a1 -= __uint_as_float(m0 & 0xffff0000u);
    a2 -= __uint_as_float(m1 << 16);
    a3 -= __uint_as_float(m1 & 0xffff0000u);
    uint32_t l0 = cvtpk(a0, a1), l1 = cvtpk(a2, a3);
    h = make_uint2(h0, h1); m = make_uint2(m0, m1); l = make_uint2(l0, l1);
}

// ---------------- async global->LDS 16B DMA ----------------
__device__ inline void dma16(const void* g, void* l) {
    __builtin_amdgcn_global_load_lds(
        (const __attribute__((address_space(1))) void*)g,
        (__attribute__((address_space(3))) void*)l, 16, 0, 0);
}

__device__ inline f32x4 mfma16(s16x8 a, s16x8 b, f32x4 c) {
    return __builtin_amdgcn_mfma_f32_16x16x32_bf16(a, b, c, 0, 0, 0);
}

// ---------------------------------------------------------------------------
// 3-way-split bf16 MFMA GEMM:  C = act(X @ W^T + bias)  (fp32-equivalent)
//   X: fp32 [M][ldx] (split on the fly, cvt_pk), W: pre-split bf16 planes.
// R3/R5-proven 2-barrier k-loop (explicit pipelining regresses, R4; hiding
// comes from multi-block/CU wave overlap, m114).
// Tiles: <64,128,MINW=4>: 36 KB LDS, 4 blocks/CU (R5/R9 measured 42% MfmaUtil)
//        <128,128,MINW=3>: 48 KB LDS, 3 blocks/CU; wave tile 64x64 (MT=NT=4)
//          -> 96 MFMA per 24 frag-reads = 1.5x better MFMA:LDS ratio (R10)
// LDS swizzle (verified R3: SQ_LDS_BANK_CONFLICT = 0): us16 idx =
//   row*32 + ((slot8 ^ ((row>>1)&3))*8 + e); A swizzled write+read;
//   B linear DMA dest + pre-swizzled global source col + swizzled read.
// Dual-param-set: blockIdx.z==1 selects the second set (co-schedules txt+sen
// in one dispatch; pass duplicates for single-set launches).
// OUT: 0 = relu; 1 = tanh with col<nreal store guard.
// 256 threads = 4 waves, 2x2 wave grid; wave tile (BM/2)x(BN/2).
// ---------------------------------------------------------------------------
template<int BM, int BN, int OUT, int MINW>
__global__ __launch_bounds__(256, MINW)
void gemm_split(const float* X, int ldx,
                const us16* Bh, const us16* Bm, const us16* Bl,
                const float* bias, float* C, int ldc, int nreal, int K,
                const float* X2, const us16* Bh2, const us16* Bm2,
                const us16* Bl2, const float* bias2, float* C2)
{
    constexpr int MT  = BM / 32;      // 16-row m-tiles per wave
    constexpr int NT  = BN / 32;      // 16-col n-tiles per wave
    constexpr int NF4 = BM / 32;      // float4 A-loads per thread per k-tile
    constexpr int LB  = BN / 64;      // B DMA chunks per wave per plane

    if (blockIdx.z) { X = X2; Bh = Bh2; Bm = Bm2; Bl = Bl2; bias = bias2; C = C2; }

    alignas(16) __shared__ us16 lds[(BM + BN) * 96];
    us16* AsH = lds;
    us16* AsM = lds + BM * 32;
    us16* AsL = lds + BM * 64;
    us16* BsH = lds + BM * 96;
    us16* BsM = lds + BM * 96 + BN * 32;
    us16* BsL = lds + BM * 96 + BN * 64;

    const int tid  = threadIdx.x;
    const int lane = tid & 63;
    const int wid  = tid >> 6;
    const int bm   = blockIdx.x * BM;
    const int bn   = blockIdx.y * BN;
    const int lm   = lane & 15;       // fragment row/col within 16
    const int kb   = lane >> 4;       // k-quad 0..3
    const int wm   = (wid >> 1) * (BM / 2);
    const int wn   = (wid & 1) * (BN / 2);

    // A staging map: thread covers rows arow + i*32, cols acol..acol+3
    const int arow = tid >> 3;        // 0..31
    const int acol = (tid & 7) * 4;   // 0,4,..,28
    const int asw  = ((arow >> 1) & 3) << 3;   // A write swizzle (us16 idx bits 3-4)
    const int fsw  = ((lm >> 1) & 3) << 3;     // fragment read swizzle

    f32x4 acc[MT][NT];
#pragma unroll
    for (int i = 0; i < MT; ++i)
#pragma unroll
        for (int j = 0; j < NT; ++j) acc[i][j] = (f32x4){0.f, 0.f, 0.f, 0.f};

    float4 pref[NF4];
#pragma unroll
    for (int i = 0; i < NF4; ++i)
        pref[i] = *(const float4*)(X + (size_t)(bm + i * 32 + arow) * ldx + acol);

    // B DMA: linear dest (wave-uniform base + lane*16B), pre-swizzled src col
    const int bcol = ((lane & 3) ^ ((lane >> 3) & 3)) * 8;

    for (int k0 = 0; k0 < K; k0 += 32) {
        __syncthreads();   // previous compute done; LDS reusable
        // ---- split prefetched A into hi/mid/lo LDS planes (swizzled) ----
#pragma unroll
        for (int i = 0; i < NF4; ++i) {
            const int r = i * 32 + arow;
            uint2 h, m, l;
            split4pk(pref[i], h, m, l);
            *(uint2*)&AsH[r * 32 + (acol ^ asw)] = h;
            *(uint2*)&AsM[r * 32 + (acol ^ asw)] = m;
            *(uint2*)&AsL[r * 32 + (acol ^ asw)] = l;
        }
        // ---- async DMA B tile (3 planes), linear dest + pre-swizzled src ----
#pragma unroll
        for (int q = 0; q < LB; ++q) {
            const int rb = wid * (LB * 16) + q * 16;          // wave-uniform
            const int gr = bn + rb + (lane >> 2);
            const int gc = k0 + bcol;
            dma16(Bh + (size_t)gr * K + gc, &BsH[rb * 32]);
            dma16(Bm + (size_t)gr * K + gc, &BsM[rb * 32]);
            dma16(Bl + (size_t)gr * K + gc, &BsL[rb * 32]);
        }
        // ---- prefetch A for next k-tile ----
        if (k0 + 32 < K) {
#pragma unroll
            for (int i = 0; i < NF4; ++i)
                pref[i] = *(const float4*)(X + (size_t)(bm + i * 32 + arow) * ldx
                                           + (k0 + 32) + acol);
        }
        __syncthreads();   // staging visible (compiler drains vmcnt+lgkm)

        // ---- MFMA phase: 6 product tiers (hh, hm, mh, hl, mm, lh) ----
        s16x8 ah[MT], am[MT], al[MT];
#pragma unroll
        for (int mt = 0; mt < MT; ++mt) {
            const int off = (wm + mt * 16 + lm) * 32 + (kb * 8 ^ fsw);
            ah[mt] = *(const s16x8*)&AsH[off];
            am[mt] = *(const s16x8*)&AsM[off];
            al[mt] = *(const s16x8*)&AsL[off];
        }
#pragma unroll
        for (int nt = 0; nt < NT; ++nt) {
            const int off = (wn + nt * 16 + lm) * 32 + (kb * 8 ^ fsw);
            s16x8 bfh = *(const s16x8*)&BsH[off];
            s16x8 bfm = *(const s16x8*)&BsM[off];
            s16x8 bfl = *(const s16x8*)&BsL[off];
#pragma unroll
            for (int mt = 0; mt < MT; ++mt) {
                acc[mt][nt] = mfma16(ah[mt], bfh, acc[mt][nt]);
                acc[mt][nt] = mfma16(ah[mt], bfm, acc[mt][nt]);
                acc[mt][nt] = mfma16(am[mt], bfh, acc[mt][nt]);
                acc[mt][nt] = mfma16(ah[mt], bfl, acc[mt][nt]);
                acc[mt][nt] = mfma16(am[mt], bfm, acc[mt][nt]);
                acc[mt][nt] = mfma16(al[mt], bfh, acc[mt][nt]);
            }
        }
    }

    // ---- epilogue: bias + activation (C/D map: col=lane&15, row=quad*4+r) ----
    float bv[NT];
#pragma unroll
    for (int nt = 0; nt < NT; ++nt) {
        const int col = bn + wn + nt * 16 + lm;
        bv[nt] = (col < nreal) ? bias[col] : 0.f;
    }
#pragma unroll
    for (int nt = 0; nt < NT; ++nt) {
        const int col = bn + wn + nt * 16 + lm;
#pragma unroll
        for (int mt = 0; mt < MT; ++mt) {
#pragma unroll
            for (int r = 0; r < 4; ++r) {
                const int row = bm + wm + mt * 16 + kb * 4 + r;
                float v = acc[mt][nt][r] + bv[nt];
                if (OUT == 0) {
                    C[(size_t)row * ldc + col] = fmaxf(v, 0.f);
                } else {
                    if (col < nreal)
                        C[(size_t)row * ldc + col] = tanhf(v);
                }
            }
        }
    }
}

// ---------------------------------------------------------------------------
// Weight pre-split into padded bf16 hi/mid/lo planes.
// Plane layout (ushort offsets): w1v [512x2048] @0, w1t @1048576, w1s @1114112,
// w2v @1179648, wfp [256x416 pad] @1245184, wfc [64x256 pad] @1351680; tot 1368064
// ---------------------------------------------------------------------------
#define WOFF_W1T 1048576
#define WOFF_W1S 1114112
#define WOFF_W2V 1179648
#define WOFF_WFP 1245184
#define WOFF_WFC 1351680
#define WTOT     1368064

__global__ void split_weights(const float* __restrict__ w1v, const float* __restrict__ w1t,
                              const float* __restrict__ w1s, const float* __restrict__ w2v,
                              const float* __restrict__ wfp, const float* __restrict__ wfc,
                              us16* __restrict__ hi, us16* __restrict__ mi,
                              us16* __restrict__ lo)
{
    int idx = blockIdx.x * 256 + threadIdx.x;
    if (idx >= WTOT) return;
    const float* src; int N, K, Kp; int local;
    if (idx < WOFF_W1T)      { src = w1v; N = 512; K = 2048; Kp = 2048; local = idx; }
    else if (idx < WOFF_W1S) { src = w1t; N = 128; K = 512;  Kp = 512;  local = idx - WOFF_W1T; }
    else if (idx < WOFF_W2V) { src = w1s; N = 128; K = 512;  Kp = 512;  local = idx - WOFF_W1S; }
    else if (idx < WOFF_WFP) { src = w2v; N = 128; K = 512;  Kp = 512;  local = idx - WOFF_W2V; }
    else if (idx < WOFF_WFC) { src = wfp; N = 256; K = 388;  Kp = 416;  local = idx - WOFF_WFP; }
    else                     { src = wfc; N = 36;  K = 256;  Kp = 256;  local = idx - WOFF_WFC; }
    int n = local / Kp, k = local % Kp;
    float v = (n < N && k < K) ? src[(size_t)n * K + k] : 0.f;
    us16 h, m, l;
    split3(v, h, m, l);
    hi[idx] = h; mi[idx] = m; lo[idx] = l;
}

// ---------------------------------------------------------------------------
// pos branch + cat K-padding: cat cols [256,260) = relu(pos), [388,416) = 0
// ---------------------------------------------------------------------------
__global__ void pos_pad(const float* __restrict__ seq, float* __restrict__ cat)
{
    int idx = blockIdx.x * 256 + threadIdx.x;
    if (idx >= MROWS * 32) return;
    int row = idx >> 5, j = idx & 31;
    if (j < 4) {
        float v = seq[(size_t)row * 3076 + 2560 + j];
        cat[(size_t)row * 416 + 256 + j] = fmaxf(v, 0.f);
    } else {
        cat[(size_t)row * 416 + 388 + (j - 4)] = 0.f;
    }
}

// ---------------------------------------------------------------------------
// Sinkhorn (verified in R2)
// ---------------------------------------------------------------------------
__global__ __launch_bounds__(256)
void sinkhorn_kernel(const float* __restrict__ Z, float* __restrict__ out)
{
    __shared__ float A[NMAT][NMAT + 1];
    __shared__ float lse[NMAT];
    const int b = blockIdx.x;
    const int tid = threadIdx.x;
    const float* zb = Z + (size_t)b * NMAT * NMAT;

    for (int idx = tid; idx < NMAT * NMAT; idx += 256)
        A[idx / NMAT][idx % NMAT] = expf(zb[idx] * TAU_INV);
    __syncthreads();

    for (int it = 0; it < 20; ++it) {
        if (tid < NMAT * 4) {
            int r = tid >> 2, g = tid & 3;
            float m = -3.402823466e38f;
            for (int j = g; j < NMAT; j += 4) m = fmaxf(m, A[r][j]);
            m = fmaxf(m, __shfl_xor(m, 2, 4));
            m = fmaxf(m, __shfl_xor(m, 1, 4));
            float s = 0.f;
            for (int j = g; j < NMAT; j += 4) s += expf(A[r][j] - m);
            s += __shfl_xor(s, 2, 4);
            s += __shfl_xor(s, 1, 4);
            if (g == 0) lse[r] = m + logf(s);
        }
        __syncthreads();
        for (int idx = tid; idx < NMAT * NMAT; idx += 256)
            A[idx / NMAT][idx % NMAT] -= lse[idx / NMAT];
        __syncthreads();

        if (tid < NMAT * 4) {
            int c = tid >> 2, g = tid & 3;
            float m = -3.402823466e38f;
            for (int i = g; i < NMAT; i += 4) m = fmaxf(m, A[i][c]);
            m = fmaxf(m, __shfl_xor(m, 2, 4));
            m = fmaxf(m, __shfl_xor(m, 1, 4));
            float s = 0.f;
            for (int i = g; i < NMAT; i += 4) s += expf(A[i][c] - m);
            s += __shfl_xor(s, 2, 4);
            s += __shfl_xor(s, 1, 4);
            if (g == 0) lse[c] = m + logf(s);
        }
        __syncthreads();
        for (int idx = tid; idx < NMAT * NMAT; idx += 256)
            A[idx / NMAT][idx % NMAT] -= lse[idx % NMAT];
        __syncthreads();
    }

    for (int idx = tid; idx < NMAT * NMAT; idx += 256)
        out[(size_t)b * NMAT * NMAT + idx] = expf(A[idx / NMAT][idx % NMAT]);
}

// ---------------------------------------------------------------------------
extern "C" void kernel_launch(void* const* d_in, const int* in_sizes, int n_in,
                              void* d_out, int out_size, void* d_ws, size_t ws_size,
                              hipStream_t stream)
{
    const float* seq = (const float*)d_in[0];
    const float* W1t = (const float*)d_in[1];
    const float* b1t = (const float*)d_in[2];
    const float* W1v = (const float*)d_in[3];
    const float* b1v = (const float*)d_in[4];
    const float* W2v = (const float*)d_in[5];
    const float* b2v = (const float*)d_in[6];
    const float* W1s = (const float*)d_in[7];
    const float* b1s = (const float*)d_in[8];
    const float* Wfp = (const float*)d_in[9];
    const float* bfp = (const float*)d_in[10];
    const float* Wfc = (const float*)d_in[11];
    const float* bfc = (const float*)d_in[12];

    float* wsF = (float*)d_ws;
    dim3 blk(256);

    // Full-M layout needs 76.63 MB (R9-verified working); fallback otherwise.
    const bool full = ws_size >= (size_t)19156992 * 4;

    if (full) {
        // ws layout (float offsets), full-M:
        //   [0, 9437184)         : vis1 (18432x512); later h256 (18432x256)
        //   [9437184, 17104896)  : cat (18432x416); later logits
        //   [17104896, +2052096) : weight planes hi/mid/lo (3 x WTOT us16)
        float* vis1buf = wsF;
        float* h256    = wsF;
        float* cat     = wsF + 9437184;
        float* logits  = wsF + 9437184;
        us16*  Whi     = (us16*)(wsF + 17104896);
        us16*  Wmi     = Whi + WTOT;
        us16*  Wlo     = Wmi + WTOT;

        split_weights<<<dim3((WTOT + 255) / 256), blk, 0, stream>>>(
            W1v, W1t, W1s, W2v, Wfp, Wfc, Whi, Wmi, Wlo);
        pos_pad<<<dim3((MROWS * 32 + 255) / 256), blk, 0, stream>>>(seq, cat);
        // txt & sen fused (blockIdx.z selects param set)
        gemm_split<64, 128, 0, 4><<<dim3(MROWS / 64, 1, 2), blk, 0, stream>>>(
            seq, 3076, Whi + WOFF_W1T, Wmi + WOFF_W1T, Wlo + WOFF_W1T, b1t,
            cat, 416, 128, 512,
            seq + 2564, Whi + WOFF_W1S, Wmi + WOFF_W1S, Wlo + WOFF_W1S, b1s,
            cat + 260);
        // vis1 full-M, 128x128 tile (R10): 144x4 = 576 blocks, 48 KB LDS,
        // wave tile 64x64 -> 96 MFMA / 24 frag-reads per k-step
        gemm_split<128, 128, 0, 3><<<dim3(MROWS / 128, 4, 1), blk, 0, stream>>>(
            seq + 512, 3076, Whi, Wmi, Wlo, b1v, vis1buf, 512, 512, 2048,
            seq + 512, Whi, Wmi, Wlo, b1v, vis1buf);
        // vis2 full-M: BN=64, y=2 -> 576 blocks (24 KB LDS)
        gemm_split<64, 64, 0, 4><<<dim3(MROWS / 64, 2, 1), blk, 0, stream>>>(
            vis1buf, 512, Whi + WOFF_W2V, Wmi + WOFF_W2V, Wlo + WOFF_W2V, b2v,
            cat + 128, 416, 128, 512,
            vis1buf, Whi + WOFF_W2V, Wmi + WOFF_W2V, Wlo + WOFF_W2V, b2v,
            cat + 128);
        // fc_pos: (M,416)->256 relu -> h256 (overlays vis1buf, now dead)
        gemm_split<64, 128, 0, 4><<<dim3(MROWS / 64, 2, 1), blk, 0, stream>>>(
            cat, 416, Whi + WOFF_WFP, Wmi + WOFF_WFP, Wlo + WOFF_WFP, bfp,
            h256, 256, 256, 416,
            cat, Whi + WOFF_WFP, Wmi + WOFF_WFP, Wlo + WOFF_WFP, bfp, h256);
        // fc: (M,256)->36 tanh -> logits (overlays cat, now dead)
        gemm_split<64, 64, 1, 4><<<dim3(MROWS / 64, 1, 1), blk, 0, stream>>>(
            h256, 256, Whi + WOFF_WFC, Wmi + WOFF_WFC, Wlo + WOFF_WFC, bfc,
            logits, 36, 36, 256,
            h256, Whi + WOFF_WFC, Wmi + WOFF_WFC, Wlo + WOFF_WFC, bfc, logits);
        sinkhorn_kernel<<<dim3(BATCH), blk, 0, stream>>>(logits, (float*)d_out);
    } else {
        // ---- R5-proven half-M fallback (57.8 MB) ----
        float* vis1buf = wsF;
        float* h256    = wsF;
        float* cat     = wsF + 4718592;
        float* logits  = wsF + 4718592;
        us16*  Whi     = (us16*)(wsF + 12386304);
        us16*  Wmi     = Whi + WTOT;
        us16*  Wlo     = Wmi + WTOT;

        split_weights<<<dim3((WTOT + 255) / 256), blk, 0, stream>>>(
            W1v, W1t, W1s, W2v, Wfp, Wfc, Whi, Wmi, Wlo);
        pos_pad<<<dim3((MROWS * 32 + 255) / 256), blk, 0, stream>>>(seq, cat);
        gemm_split<64, 128, 0, 4><<<dim3(MROWS / 64, 1, 2), blk, 0, stream>>>(
            seq, 3076, Whi + WOFF_W1T, Wmi + WOFF_W1T, Wlo + WOFF_W1T, b1t,
            cat, 416, 128, 512,
            seq + 2564, Whi + WOFF_W1S, Wmi + WOFF_W1S, Wlo + WOFF_W1S, b1s,
            cat + 260);
        for (int h = 0; h < 2; ++h) {
            const float* xh = seq + 512 + (size_t)h * MHALF * 3076;
            float* ch = cat + 128 + (size_t)h * MHALF * 416;
            gemm_split<64, 128, 0, 4><<<dim3(MHALF / 64, 4, 1), blk, 0, stream>>>(
                xh, 3076, Whi, Wmi, Wlo, b1v, vis1buf, 512, 512, 2048,
                xh, Whi, Wmi, Wlo, b1v, vis1buf);
            gemm_split<64, 128, 0, 4><<<dim3(MHALF / 64, 1, 1), blk, 0, stream>>>(
                vis1buf, 512, Whi + WOFF_W2V, Wmi + WOFF_W2V, Wlo + WOFF_W2V, b2v,
                ch, 416, 128, 512,
                vis1buf, Whi + WOFF_W2V, Wmi + WOFF_W2V, Wlo + WOFF_W2V, b2v, ch);
        }
        gemm_split<64, 128, 0, 4><<<dim3(MROWS / 64, 2, 1), blk, 0, stream>>>(
            cat, 416, Whi + WOFF_WFP, Wmi + WOFF_WFP, Wlo + WOFF_WFP, bfp,
            h256, 256, 256, 416,
            cat, Whi + WOFF_WFP, Wmi + WOFF_WFP, Wlo + WOFF_WFP, bfp, h256);
        gemm_split<64, 64, 1, 4><<<dim3(MROWS / 64, 1, 1), blk, 0, stream>>>(
            h256, 256, Whi + WOFF_WFC, Wmi + WOFF_WFC, Wlo + WOFF_WFC, bfc,
            logits, 36, 36, 256,
            h256, Whi + WOFF_WFC, Wmi + WOFF_WFC, Wlo + WOFF_WFC, bfc, logits);
        sinkhorn_kernel<<<dim3(BATCH), blk, 0, stream>>>(logits, (float*)d_out);
    }
}

// Round 12
// 595.292 us; speedup vs baseline: 1.4861x; 1.1038x over previous
//
#include <hip/hip_runtime.h>
#include <cstddef>
#include <cstdint>
#include <cmath>

#define TAU_INV 20.0f
#define NMAT 36
#define BATCH 512
#define MROWS 18432   // 512 * 36
#define MHALF 9216

typedef unsigned short us16;
typedef __attribute__((ext_vector_type(8))) short s16x8;   // 8 bf16 = 4 VGPRs
typedef __attribute__((ext_vector_type(4))) float f32x4;

// ---------------- bf16 helpers (RNE) ----------------
__device__ inline us16 f2bf(float x) {
    uint32_t u = __float_as_uint(x);
    u += 0x7fff + ((u >> 16) & 1);
    return (us16)(u >> 16);
}
__device__ inline float bf2f(us16 h) {
    return __uint_as_float(((uint32_t)h) << 16);
}
// 3-way split (weights pre-split kernel; gemm uses only h,m planes now)
__device__ inline void split3(float v, us16& h, us16& m, us16& l) {
    h = f2bf(v);
    float r1 = v - bf2f(h);
    m = f2bf(r1);
    l = f2bf(r1 - bf2f(m));
}

// packed f32x2 -> bf16x2 convert (T12 recipe; no builtin on gfx950)
__device__ inline uint32_t cvtpk(float lo, float hi) {
    uint32_t d;
    asm("v_cvt_pk_bf16_f32 %0, %1, %2" : "=v"(d) : "v"(lo), "v"(hi));
    return d;
}
// 2-way split of 4 floats into packed h/m bf16 plane words.
// 4-tier product (h+m)(h+m) is EXACT; missing x*yl+xl*y ~2^-18 rel,
// ~5e-6 per layer after sqrt(K) cancellation (R11 analysis).
__device__ inline void split2pk(const float4& v, uint2& h, uint2& m) {
    uint32_t h0 = cvtpk(v.x, v.y), h1 = cvtpk(v.z, v.w);
    float a0 = v.x - __uint_as_float(h0 << 16);
    float a1 = v.y - __uint_as_float(h0 & 0xffff0000u);
    float a2 = v.z - __uint_as_float(h1 << 16);
    float a3 = v.w - __uint_as_float(h1 & 0xffff0000u);
    uint32_t m0 = cvtpk(a0, a1), m1 = cvtpk(a2, a3);
    h = make_uint2(h0, h1); m = make_uint2(m0, m1);
}

// ---------------- async global->LDS 16B DMA ----------------
__device__ inline void dma16(const void* g, void* l) {
    __builtin_amdgcn_global_load_lds(
        (const __attribute__((address_space(1))) void*)g,
        (__attribute__((address_space(3))) void*)l, 16, 0, 0);
}

__device__ inline f32x4 mfma16(s16x8 a, s16x8 b, f32x4 c) {
    return __builtin_amdgcn_mfma_f32_16x16x32_bf16(a, b, c, 0, 0, 0);
}

// ---------------------------------------------------------------------------
// 2-plane-split bf16 MFMA GEMM:  C = act(X @ W^T + bias)
//   4 tiers (hh,hm,mh,mm) = exact (h+m)x(h+m); error ~2^-18 rel per product.
// k-loop (R11): barrier -> DMA-B issue -> A-prefetch issue (prefN ping-pong)
//   -> split-VALU (covers load latency) -> barrier -> MFMA.  (R10 counters:
//   dominant cost was load latency exposed at barrier2; hoist gives loads
//   ~250 cyc of flight. Explicit dbuf regresses (R4); TLP does the rest.)
// LDS: 2 planes A + 2 planes B, (BM+BN)*64 us16: <128,128>=32KB, <64,128>=24KB.
// LDS swizzle (verified R3: SQ_LDS_BANK_CONFLICT = 0): us16 idx =
//   row*32 + ((slot8 ^ ((row>>1)&3))*8 + e); A swizzled write+read;
//   B linear DMA dest + pre-swizzled global source col + swizzled read.
// Dual-param-set: blockIdx.z==1 selects the second set (co-schedules txt+sen).
// OUT: 0 = relu; 1 = tanh with col<nreal store guard.
// 256 threads = 4 waves, 2x2 wave grid; wave tile (BM/2)x(BN/2).
// ---------------------------------------------------------------------------
template<int BM, int BN, int OUT, int MINW>
__global__ __launch_bounds__(256, MINW)
void gemm_split(const float* X, int ldx,
                const us16* Bh, const us16* Bm,
                const float* bias, float* C, int ldc, int nreal, int K,
                const float* X2, const us16* Bh2, const us16* Bm2,
                const float* bias2, float* C2)
{
    constexpr int MT  = BM / 32;      // 16-row m-tiles per wave
    constexpr int NT  = BN / 32;      // 16-col n-tiles per wave
    constexpr int NF4 = BM / 32;      // float4 A-loads per thread per k-tile
    constexpr int LB  = BN / 64;      // B DMA chunks per wave per plane

    if (blockIdx.z) { X = X2; Bh = Bh2; Bm = Bm2; bias = bias2; C = C2; }

    alignas(16) __shared__ us16 lds[(BM + BN) * 64];
    us16* AsH = lds;
    us16* AsM = lds + BM * 32;
    us16* BsH = lds + BM * 64;
    us16* BsM = lds + BM * 64 + BN * 32;

    const int tid  = threadIdx.x;
    const int lane = tid & 63;
    const int wid  = tid >> 6;
    const int bm   = blockIdx.x * BM;
    const int bn   = blockIdx.y * BN;
    const int lm   = lane & 15;       // fragment row/col within 16
    const int kb   = lane >> 4;       // k-quad 0..3
    const int wm   = (wid >> 1) * (BM / 2);
    const int wn   = (wid & 1) * (BN / 2);

    // A staging map: thread covers rows arow + i*32, cols acol..acol+3
    const int arow = tid >> 3;        // 0..31
    const int acol = (tid & 7) * 4;   // 0,4,..,28
    const int asw  = ((arow >> 1) & 3) << 3;   // A write swizzle (us16 idx bits 3-4)
    const int fsw  = ((lm >> 1) & 3) << 3;     // fragment read swizzle

    f32x4 acc[MT][NT];
#pragma unroll
    for (int i = 0; i < MT; ++i)
#pragma unroll
        for (int j = 0; j < NT; ++j) acc[i][j] = (f32x4){0.f, 0.f, 0.f, 0.f};

    float4 pref[NF4];
#pragma unroll
    for (int i = 0; i < NF4; ++i)
        pref[i] = *(const float4*)(X + (size_t)(bm + i * 32 + arow) * ldx + acol);

    // B DMA: linear dest (wave-uniform base + lane*16B), pre-swizzled src col
    const int bcol = ((lane & 3) ^ ((lane >> 3) & 3)) * 8;

    for (int k0 = 0; k0 < K; k0 += 32) {
        __syncthreads();   // previous compute done; LDS reusable
        // ---- hoisted: async DMA B tile (2 planes) — flies under the split ----
#pragma unroll
        for (int q = 0; q < LB; ++q) {
            const int rb = wid * (LB * 16) + q * 16;          // wave-uniform
            const int gr = bn + rb + (lane >> 2);
            const int gc = k0 + bcol;
            dma16(Bh + (size_t)gr * K + gc, &BsH[rb * 32]);
            dma16(Bm + (size_t)gr * K + gc, &BsM[rb * 32]);
        }
        // ---- hoisted: A prefetch for next k-tile (ping-pong regs) ----
        float4 prefN[NF4];
        if (k0 + 32 < K) {
#pragma unroll
            for (int i = 0; i < NF4; ++i)
                prefN[i] = *(const float4*)(X + (size_t)(bm + i * 32 + arow) * ldx
                                            + (k0 + 32) + acol);
        }
        // ---- split current A into h/m LDS planes (covers load latency) ----
#pragma unroll
        for (int i = 0; i < NF4; ++i) {
            const int r = i * 32 + arow;
            uint2 h, m;
            split2pk(pref[i], h, m);
            *(uint2*)&AsH[r * 32 + (acol ^ asw)] = h;
            *(uint2*)&AsM[r * 32 + (acol ^ asw)] = m;
        }
        if (k0 + 32 < K) {
#pragma unroll
            for (int i = 0; i < NF4; ++i) pref[i] = prefN[i];
        }
        __syncthreads();   // staging visible (compiler drains vmcnt+lgkm)

        // ---- MFMA phase: 4 tiers (hh, hm, mh, mm) ----
        s16x8 ah[MT], am[MT];
#pragma unroll
        for (int mt = 0; mt < MT; ++mt) {
            const int off = (wm + mt * 16 + lm) * 32 + (kb * 8 ^ fsw);
            ah[mt] = *(const s16x8*)&AsH[off];
            am[mt] = *(const s16x8*)&AsM[off];
        }
#pragma unroll
        for (int nt = 0; nt < NT; ++nt) {
            const int off = (wn + nt * 16 + lm) * 32 + (kb * 8 ^ fsw);
            s16x8 bfh = *(const s16x8*)&BsH[off];
            s16x8 bfm = *(const s16x8*)&BsM[off];
#pragma unroll
            for (int mt = 0; mt < MT; ++mt) {
                acc[mt][nt] = mfma16(ah[mt], bfh, acc[mt][nt]);
                acc[mt][nt] = mfma16(ah[mt], bfm, acc[mt][nt]);
                acc[mt][nt] = mfma16(am[mt], bfh, acc[mt][nt]);
                acc[mt][nt] = mfma16(am[mt], bfm, acc[mt][nt]);
            }
        }
    }

    // ---- epilogue: bias + activation (C/D map: col=lane&15, row=quad*4+r) ----
    float bv[NT];
#pragma unroll
    for (int nt = 0; nt < NT; ++nt) {
        const int col = bn + wn + nt * 16 + lm;
        bv[nt] = (col < nreal) ? bias[col] : 0.f;
    }
#pragma unroll
    for (int nt = 0; nt < NT; ++nt) {
        const int col = bn + wn + nt * 16 + lm;
#pragma unroll
        for (int mt = 0; mt < MT; ++mt) {
#pragma unroll
            for (int r = 0; r < 4; ++r) {
                const int row = bm + wm + mt * 16 + kb * 4 + r;
                float v = acc[mt][nt][r] + bv[nt];
                if (OUT == 0) {
                    C[(size_t)row * ldc + col] = fmaxf(v, 0.f);
                } else {
                    if (col < nreal)
                        C[(size_t)row * ldc + col] = tanhf(v);
                }
            }
        }
    }
}

// ---------------------------------------------------------------------------
// Weight pre-split into padded bf16 hi/mid/lo planes (lo now unused by gemm).
// Plane layout (ushort offsets): w1v [512x2048] @0, w1t @1048576, w1s @1114112,
// w2v @1179648, wfp [256x416 pad] @1245184, wfc [64x256 pad] @1351680; tot 1368064
// ---------------------------------------------------------------------------
#define WOFF_W1T 1048576
#define WOFF_W1S 1114112
#define WOFF_W2V 1179648
#define WOFF_WFP 1245184
#define WOFF_WFC 1351680
#define WTOT     1368064

__global__ void split_weights(const float* __restrict__ w1v, const float* __restrict__ w1t,
                              const float* __restrict__ w1s, const float* __restrict__ w2v,
                              const float* __restrict__ wfp, const float* __restrict__ wfc,
                              us16* __restrict__ hi, us16* __restrict__ mi,
                              us16* __restrict__ lo)
{
    int idx = blockIdx.x * 256 + threadIdx.x;
    if (idx >= WTOT) return;
    const float* src; int N, K, Kp; int local;
    if (idx < WOFF_W1T)      { src = w1v; N = 512; K = 2048; Kp = 2048; local = idx; }
    else if (idx < WOFF_W1S) { src = w1t; N = 128; K = 512;  Kp = 512;  local = idx - WOFF_W1T; }
    else if (idx < WOFF_W2V) { src = w1s; N = 128; K = 512;  Kp = 512;  local = idx - WOFF_W1S; }
    else if (idx < WOFF_WFP) { src = w2v; N = 128; K = 512;  Kp = 512;  local = idx - WOFF_W2V; }
    else if (idx < WOFF_WFC) { src = wfp; N = 256; K = 388;  Kp = 416;  local = idx - WOFF_WFP; }
    else                     { src = wfc; N = 36;  K = 256;  Kp = 256;  local = idx - WOFF_WFC; }
    int n = local / Kp, k = local % Kp;
    float v = (n < N && k < K) ? src[(size_t)n * K + k] : 0.f;
    us16 h, m, l;
    split3(v, h, m, l);
    hi[idx] = h; mi[idx] = m; lo[idx] = l;
}

// ---------------------------------------------------------------------------
// pos branch + cat K-padding: cat cols [256,260) = relu(pos), [388,416) = 0
// ---------------------------------------------------------------------------
__global__ void pos_pad(const float* __restrict__ seq, float* __restrict__ cat)
{
    int idx = blockIdx.x * 256 + threadIdx.x;
    if (idx >= MROWS * 32) return;
    int row = idx >> 5, j = idx & 31;
    if (j < 4) {
        float v = seq[(size_t)row * 3076 + 2560 + j];
        cat[(size_t)row * 416 + 256 + j] = fmaxf(v, 0.f);
    } else {
        cat[(size_t)row * 416 + 388 + (j - 4)] = 0.f;
    }
}

// ---------------------------------------------------------------------------
// Sinkhorn (verified in R2)
// ---------------------------------------------------------------------------
__global__ __launch_bounds__(256)
void sinkhorn_kernel(const float* __restrict__ Z, float* __restrict__ out)
{
    __shared__ float A[NMAT][NMAT + 1];
    __shared__ float lse[NMAT];
    const int b = blockIdx.x;
    const int tid = threadIdx.x;
    const float* zb = Z + (size_t)b * NMAT * NMAT;

    for (int idx = tid; idx < NMAT * NMAT; idx += 256)
        A[idx / NMAT][idx % NMAT] = expf(zb[idx] * TAU_INV);
    __syncthreads();

    for (int it = 0; it < 20; ++it) {
        if (tid < NMAT * 4) {
            int r = tid >> 2, g = tid & 3;
            float m = -3.402823466e38f;
            for (int j = g; j < NMAT; j += 4) m = fmaxf(m, A[r][j]);
            m = fmaxf(m, __shfl_xor(m, 2, 4));
            m = fmaxf(m, __shfl_xor(m, 1, 4));
            float s = 0.f;
            for (int j = g; j < NMAT; j += 4) s += expf(A[r][j] - m);
            s += __shfl_xor(s, 2, 4);
            s += __shfl_xor(s, 1, 4);
            if (g == 0) lse[r] = m + logf(s);
        }
        __syncthreads();
        for (int idx = tid; idx < NMAT * NMAT; idx += 256)
            A[idx / NMAT][idx % NMAT] -= lse[idx / NMAT];
        __syncthreads();

        if (tid < NMAT * 4) {
            int c = tid >> 2, g = tid & 3;
            float m = -3.402823466e38f;
            for (int i = g; i < NMAT; i += 4) m = fmaxf(m, A[i][c]);
            m = fmaxf(m, __shfl_xor(m, 2, 4));
            m = fmaxf(m, __shfl_xor(m, 1, 4));
            float s = 0.f;
            for (int i = g; i < NMAT; i += 4) s += expf(A[i][c] - m);
            s += __shfl_xor(s, 2, 4);
            s += __shfl_xor(s, 1, 4);
            if (g == 0) lse[c] = m + logf(s);
        }
        __syncthreads();
        for (int idx = tid; idx < NMAT * NMAT; idx += 256)
            A[idx / NMAT][idx % NMAT] -= lse[idx % NMAT];
        __syncthreads();
    }

    for (int idx = tid; idx < NMAT * NMAT; idx += 256)
        out[(size_t)b * NMAT * NMAT + idx] = expf(A[idx / NMAT][idx % NMAT]);
}

// ---------------------------------------------------------------------------
extern "C" void kernel_launch(void* const* d_in, const int* in_sizes, int n_in,
                              void* d_out, int out_size, void* d_ws, size_t ws_size,
                              hipStream_t stream)
{
    const float* seq = (const float*)d_in[0];
    const float* W1t = (const float*)d_in[1];
    const float* b1t = (const float*)d_in[2];
    const float* W1v = (const float*)d_in[3];
    const float* b1v = (const float*)d_in[4];
    const float* W2v = (const float*)d_in[5];
    const float* b2v = (const float*)d_in[6];
    const float* W1s = (const float*)d_in[7];
    const float* b1s = (const float*)d_in[8];
    const float* Wfp = (const float*)d_in[9];
    const float* bfp = (const float*)d_in[10];
    const float* Wfc = (const float*)d_in[11];
    const float* bfc = (const float*)d_in[12];

    float* wsF = (float*)d_ws;
    dim3 blk(256);

    // Full-M layout needs 76.63 MB (R9/R10-verified working); fallback otherwise.
    const bool full = ws_size >= (size_t)19156992 * 4;

    if (full) {
        // ws layout (float offsets), full-M:
        //   [0, 9437184)         : vis1 (18432x512); later h256 (18432x256)
        //   [9437184, 17104896)  : cat (18432x416); later logits
        //   [17104896, +2052096) : weight planes hi/mid/lo (3 x WTOT us16)
        float* vis1buf = wsF;
        float* h256    = wsF;
        float* cat     = wsF + 9437184;
        float* logits  = wsF + 9437184;
        us16*  Whi     = (us16*)(wsF + 17104896);
        us16*  Wmi     = Whi + WTOT;
        us16*  Wlo     = Wmi + WTOT;

        split_weights<<<dim3((WTOT + 255) / 256), blk, 0, stream>>>(
            W1v, W1t, W1s, W2v, Wfp, Wfc, Whi, Wmi, Wlo);
        pos_pad<<<dim3((MROWS * 32 + 255) / 256), blk, 0, stream>>>(seq, cat);
        // txt & sen fused (blockIdx.z selects param set)
        gemm_split<64, 128, 0, 4><<<dim3(MROWS / 64, 1, 2), blk, 0, stream>>>(
            seq, 3076, Whi + WOFF_W1T, Wmi + WOFF_W1T, b1t,
            cat, 416, 128, 512,
            seq + 2564, Whi + WOFF_W1S, Wmi + WOFF_W1S, b1s,
            cat + 260);
        // vis1 full-M, 128x128 tile: 144x4 = 576 blocks, 32 KB LDS
        gemm_split<128, 128, 0, 3><<<dim3(MROWS / 128, 4, 1), blk, 0, stream>>>(
            seq + 512, 3076, Whi, Wmi, b1v, vis1buf, 512, 512, 2048,
            seq + 512, Whi, Wmi, b1v, vis1buf);
        // vis2 full-M: BN=64, y=2 -> 576 blocks (16 KB LDS)
        gemm_split<64, 64, 0, 4><<<dim3(MROWS / 64, 2, 1), blk, 0, stream>>>(
            vis1buf, 512, Whi + WOFF_W2V, Wmi + WOFF_W2V, b2v,
            cat + 128, 416, 128, 512,
            vis1buf, Whi + WOFF_W2V, Wmi + WOFF_W2V, b2v,
            cat + 128);
        // fc_pos: (M,416)->256 relu -> h256 (overlays vis1buf, now dead)
        gemm_split<64, 128, 0, 4><<<dim3(MROWS / 64, 2, 1), blk, 0, stream>>>(
            cat, 416, Whi + WOFF_WFP, Wmi + WOFF_WFP, bfp,
            h256, 256, 256, 416,
            cat, Whi + WOFF_WFP, Wmi + WOFF_WFP, bfp, h256);
        // fc: (M,256)->36 tanh -> logits (overlays cat, now dead)
        gemm_split<64, 64, 1, 4><<<dim3(MROWS / 64, 1, 1), blk, 0, stream>>>(
            h256, 256, Whi + WOFF_WFC, Wmi + WOFF_WFC, bfc,
            logits, 36, 36, 256,
            h256, Whi + WOFF_WFC, Wmi + WOFF_WFC, bfc, logits);
        sinkhorn_kernel<<<dim3(BATCH), blk, 0, stream>>>(logits, (float*)d_out);
    } else {
        // ---- half-M fallback (57.8 MB), same 2-plane kernel ----
        float* vis1buf = wsF;
        float* h256    = wsF;
        float* cat     = wsF + 4718592;
        float* logits  = wsF + 4718592;
        us16*  Whi     = (us16*)(wsF + 12386304);
        us16*  Wmi     = Whi + WTOT;
        us16*  Wlo     = Wmi + WTOT;

        split_weights<<<dim3((WTOT + 255) / 256), blk, 0, stream>>>(
            W1v, W1t, W1s, W2v, Wfp, Wfc, Whi, Wmi, Wlo);
        pos_pad<<<dim3((MROWS * 32 + 255) / 256), blk, 0, stream>>>(seq, cat);
        gemm_split<64, 128, 0, 4><<<dim3(MROWS / 64, 1, 2), blk, 0, stream>>>(
            seq, 3076, Whi + WOFF_W1T, Wmi + WOFF_W1T, b1t,
            cat, 416, 128, 512,
            seq + 2564, Whi + WOFF_W1S, Wmi + WOFF_W1S, b1s,
            cat + 260);
        for (int h = 0; h < 2; ++h) {
            const float* xh = seq + 512 + (size_t)h * MHALF * 3076;
            float* ch = cat + 128 + (size_t)h * MHALF * 416;
            gemm_split<128, 128, 0, 3><<<dim3(MHALF / 128, 4, 1), blk, 0, stream>>>(
                xh, 3076, Whi, Wmi, b1v, vis1buf, 512, 512, 2048,
                xh, Whi, Wmi, b1v, vis1buf);
            gemm_split<64, 64, 0, 4><<<dim3(MHALF / 64, 2, 1), blk, 0, stream>>>(
                vis1buf, 512, Whi + WOFF_W2V, Wmi + WOFF_W2V, b2v,
                ch, 416, 128, 512,
                vis1buf, Whi + WOFF_W2V, Wmi + WOFF_W2V, b2v, ch);
        }
        gemm_split<64, 128, 0, 4><<<dim3(MROWS / 64, 2, 1), blk, 0, stream>>>(
            cat, 416, Whi + WOFF_WFP, Wmi + WOFF_WFP, bfp,
            h256, 256, 256, 416,
            cat, Whi + WOFF_WFP, Wmi + WOFF_WFP, bfp, h256);
        gemm_split<64, 64, 1, 4><<<dim3(MROWS / 64, 1, 1), blk, 0, stream>>>(
            h256, 256, Whi + WOFF_WFC, Wmi + WOFF_WFC, bfc,
            logits, 36, 36, 256,
            h256, Whi + WOFF_WFC, Wmi + WOFF_WFC, bfc, logits);
        sinkhorn_kernel<<<dim3(BATCH), blk, 0, stream>>>(logits, (float*)d_out);
    }
}